// Round 4
// baseline (1320.906 us; speedup 1.0000x reference)
//
#include <hip/hip_runtime.h>
#include <stdint.h>

#define Bb 128
#define Nn 1024
#define Dd 512
#define Ss 64

constexpr float kScale = 0.044194173824159216f;  // 512^-0.5
constexpr float kEps = 1e-8f;

typedef __bf16 bf16x8 __attribute__((ext_vector_type(8)));
typedef float f32x4 __attribute__((ext_vector_type(4)));

__device__ inline unsigned short f2bf_rne(float x) {
  unsigned u = __builtin_bit_cast(unsigned, x);
  u += 0x7FFFu + ((u >> 16) & 1u);
  return (unsigned short)(u >> 16);
}
__device__ inline float bf2f(unsigned short h) {
  unsigned u = ((unsigned)h) << 16;
  return __builtin_bit_cast(float, u);
}

// async global->LDS, 16B per lane; LDS dest must be wave-uniform base (HW adds lane*16)
__device__ inline void gl_lds16(const void* g, void* l) {
  typedef unsigned int u32;
  auto gp = (u32 __attribute__((address_space(1)))*)(unsigned long long)(uintptr_t)g;
  auto lp = (u32 __attribute__((address_space(3)))*)(unsigned int)(uintptr_t)l;
  __builtin_amdgcn_global_load_lds(gp, lp, 16, 0, 0);
}

// f32 -> bf16 hi/lo split (a ~= hi + lo, residual ~2^-16 rel)
__global__ void cast_split(const float* __restrict__ in,
                           unsigned short* __restrict__ hi,
                           unsigned short* __restrict__ lo,
                           int n4) {
  int i = blockIdx.x * blockDim.x + threadIdx.x;
  const int stride = gridDim.x * blockDim.x;
  for (; i < n4; i += stride) {
    const float4 v = ((const float4*)in)[i];
    ushort4 h, lw;
    h.x = f2bf_rne(v.x); lw.x = f2bf_rne(v.x - bf2f(h.x));
    h.y = f2bf_rne(v.y); lw.y = f2bf_rne(v.y - bf2f(h.y));
    h.z = f2bf_rne(v.z); lw.z = f2bf_rne(v.z - bf2f(h.z));
    h.w = f2bf_rne(v.w); lw.w = f2bf_rne(v.w - bf2f(h.w));
    ((ushort4*)hi)[i] = h;
    ((ushort4*)lo)[i] = lw;
  }
}

// C[M,512] = act(A[M,512] @ W[512,512]^T + bias), split bf16 expressed as a
// virtual-K bf16 GEMM: K' = 1536 over segments [Ah,Al,Ah] x [Bh,Bh,Bl]
// (= ah*bh + al*bh + ah*bl; al*bl ~2^-32, dropped).
// BM=BN=256, BK=32, 8 waves (2Mx4N), wave-tile 128x64, 16x16x32 MFMA.
// 4-deep LDS ring (4 x 32KB = 128KB), counted vmcnt(8) (3 tiles in flight),
// one barrier per K-tile, granule-XOR swizzle (pos = g ^ ((row>>1)&3)) applied
// as linear-LDS-dest + inverse-swizzled global source + swizzled ds_read.
template <int ACT>
__global__ __launch_bounds__(512, 1) void gemm_split3(
    const unsigned short* __restrict__ Ah, const unsigned short* __restrict__ Al,
    const unsigned short* __restrict__ Wh, const unsigned short* __restrict__ Wl,
    const float* __restrict__ bias,
    unsigned short* __restrict__ Ch, unsigned short* __restrict__ Cl) {
  constexpr int NT3 = 48;  // 1536 / 32
  extern __shared__ unsigned short lds[];
  const int t = threadIdx.x, l = t & 63, w = t >> 6;
  const int x = l & 15;
  const int wr = w >> 2, wc = w & 3;

  // bijective XCD-chunked swizzle (1024 blocks = 8 * 128)
  const int wg = (blockIdx.x & 7) * 128 + (blockIdx.x >> 3);
  const long rowA0 = (long)(wg >> 1) * 256;  // consecutive pairs share the A panel
  const int colB0 = (wg & 1) * 256;
  const unsigned short* Ahb = Ah + rowA0 * 512;
  const unsigned short* Alb = Al + rowA0 * 512;
  const unsigned short* Whb = Wh + (long)colB0 * 512;
  const unsigned short* Wlb = Wl + (long)colB0 * 512;

  // staging: thread t covers row r = q*128 + (t>>2), 16B granule at swizzled
  // position (t&3); inverse-swizzled source granule g0 = (t&3) ^ ((r>>1)&3)
  // (note (r>>1)&3 is invariant under r += 128).
  const int g0 = (t & 3) ^ (((t >> 2) >> 1) & 3);
  const int offT0 = (t >> 2) * 512 + g0 * 8;   // ushort offset, rows 0..127
  const int offT1 = offT0 + 65536;             // rows 128..255
  const int wdst = w * 512;                    // wave-uniform LDS chunk (ushorts)

  auto stage = [&](int kt) {
    const int seg = kt >> 4;
    const int k0 = (kt & 15) * 32;  // physical K offset (elements)
    const unsigned short* As = (seg == 1) ? Alb : Ahb;
    const unsigned short* Bs = (seg == 2) ? Wlb : Whb;
    unsigned short* lb = lds + (kt & 3) * 16384;  // 32KB ring slot
    gl_lds16(As + offT0 + k0, lb + wdst);              // A rows 0-127
    gl_lds16(As + offT1 + k0, lb + 4096 + wdst);       // A rows 128-255
    gl_lds16(Bs + offT0 + k0, lb + 8192 + wdst);       // B rows 0-127
    gl_lds16(Bs + offT1 + k0, lb + 12288 + wdst);      // B rows 128-255
  };

  // frag read: lane wants row R0+x, k-granule (l>>4); stored position
  // p = (l>>4) ^ ((x>>1)&3)  (R0 multiple of 16 -> lane-only swizzle term)
  const int p16 = ((l >> 4) ^ ((x >> 1) & 3)) * 16;       // byte
  const int abase = (wr * 128 + x) * 64 + p16;            // byte, A part
  const int bbase = 16384 + (wc * 64 + x) * 64 + p16;     // byte, B part

  f32x4 acc[8][4] = {};

  stage(0);
  stage(1);
  stage(2);

  for (int kt = 0; kt < NT3; ++kt) {
    // gate: tile kt landed. Outstanding before stage(kt+3): kt,kt+1,kt+2 (12) -> 8.
    if (kt < NT3 - 2) {
      asm volatile("s_waitcnt vmcnt(8)" ::: "memory");
    } else if (kt == NT3 - 2) {
      asm volatile("s_waitcnt vmcnt(4)" ::: "memory");
    } else {
      asm volatile("s_waitcnt vmcnt(0)" ::: "memory");
    }
    __builtin_amdgcn_s_barrier();
    __builtin_amdgcn_sched_barrier(0);
    // ring slot (kt+3)%4 was last read as tile kt-1 strictly before the barrier
    if (kt + 3 < NT3) stage(kt + 3);

    const char* bb = (const char*)lds + (kt & 3) * 32768;
    bf16x8 fb[4], fa[8];
#pragma unroll
    for (int n = 0; n < 4; n++) fb[n] = *(const bf16x8*)(bb + bbase + n * 1024);
#pragma unroll
    for (int m = 0; m < 8; m++) fa[m] = *(const bf16x8*)(bb + abase + m * 1024);
    __builtin_amdgcn_s_setprio(1);
#pragma unroll
    for (int m = 0; m < 8; m++)
#pragma unroll
      for (int n = 0; n < 4; n++)
        acc[m][n] = __builtin_amdgcn_mfma_f32_16x16x32_bf16(fa[m], fb[n], acc[m][n], 0, 0, 0);
    __builtin_amdgcn_s_setprio(0);
    __builtin_amdgcn_sched_barrier(0);
  }

  // epilogue: C/D 16x16 layout: col = l&15, row = (l>>4)*4 + r
#pragma unroll
  for (int n = 0; n < 4; n++) {
    const int col = colB0 + wc * 64 + n * 16 + x;
    const float bv = bias[col];
#pragma unroll
    for (int m = 0; m < 8; m++) {
      const long row = rowA0 + wr * 128 + m * 16 + (l >> 4) * 4;
#pragma unroll
      for (int r = 0; r < 4; r++) {
        float xv = acc[m][n][r] + bv;
        if (ACT) xv = fmaxf(xv, 0.0f);
        const unsigned short h = f2bf_rne(xv);
        const long idx = (row + r) * 512 + col;
        Ch[idx] = h;
        Cl[idx] = f2bf_rne(xv - bf2f(h));
      }
    }
  }
}

// dots[b,64,1024] = scale * slots[64,512] @ k[b,1024,512]^T  (split bf16 MFMA, f32 out)
__global__ __launch_bounds__(256) void gemm_dots_split(
    const unsigned short* __restrict__ Qh, const unsigned short* __restrict__ Ql,
    const unsigned short* __restrict__ Kh, const unsigned short* __restrict__ Kl,
    float* __restrict__ dots) {
  constexpr int K = 512, BM = 64, BN = 128, BK = 32;
  __shared__ __align__(16) unsigned short lah[BM * BK];
  __shared__ __align__(16) unsigned short lal[BM * BK];
  __shared__ __align__(16) unsigned short lbh[BN * BK];
  __shared__ __align__(16) unsigned short lbl[BN * BK];
  const int t = threadIdx.x, l = t & 63, w = t >> 6;
  const int b = blockIdx.x >> 3, bc = blockIdx.x & 7;
  const unsigned short* kh = Kh + (long)b * Nn * Dd;
  const unsigned short* kl = Kl + (long)b * Nn * Dd;
  f32x4 acc[4][2] = {};

  for (int k0 = 0; k0 < K; k0 += BK) {
    {
      const int c = t;
      const int ga = (c >> 2) * K + k0 + (c & 3) * 8;
      const int lo = (w * 64) * 8;
      gl_lds16(Qh + ga, lah + lo);
      gl_lds16(Ql + ga, lal + lo);
    }
#pragma unroll
    for (int qq = 0; qq < 2; qq++) {
      const int c = qq * 256 + t;
      const long gb = (long)(bc * BN + (c >> 2)) * K + k0 + (c & 3) * 8;
      const int lo = (qq * 256 + w * 64) * 8;
      gl_lds16(kh + gb, lbh + lo);
      gl_lds16(kl + gb, lbl + lo);
    }
    __syncthreads();
    bf16x8 ah[4], al[4], bh[2], bl[2];
#pragma unroll
    for (int m = 0; m < 4; m++) {
      const int off = (m * 16 + (l & 15)) * BK + (l >> 4) * 8;
      ah[m] = *(const bf16x8*)(lah + off);
      al[m] = *(const bf16x8*)(lal + off);
    }
#pragma unroll
    for (int n = 0; n < 2; n++) {
      const int off = (w * 32 + n * 16 + (l & 15)) * BK + (l >> 4) * 8;
      bh[n] = *(const bf16x8*)(lbh + off);
      bl[n] = *(const bf16x8*)(lbl + off);
    }
#pragma unroll
    for (int m = 0; m < 4; m++)
#pragma unroll
      for (int n = 0; n < 2; n++) {
        acc[m][n] = __builtin_amdgcn_mfma_f32_16x16x32_bf16(ah[m], bh[n], acc[m][n], 0, 0, 0);
        acc[m][n] = __builtin_amdgcn_mfma_f32_16x16x32_bf16(al[m], bh[n], acc[m][n], 0, 0, 0);
        acc[m][n] = __builtin_amdgcn_mfma_f32_16x16x32_bf16(ah[m], bl[n], acc[m][n], 0, 0, 0);
      }
    __syncthreads();
  }
  float* dp = dots + (long)b * Ss * Nn;
#pragma unroll
  for (int m = 0; m < 4; m++) {
    const int row = m * 16 + (l >> 4) * 4;
#pragma unroll
    for (int n = 0; n < 2; n++) {
      const int col = bc * BN + w * 32 + n * 16 + (l & 15);
#pragma unroll
      for (int r = 0; r < 4; r++) dp[(long)(row + r) * Nn + col] = acc[m][n][r] * kScale;
    }
  }
}

// per-batch: s_j[b,i] = sum_j dots, s_all[b] = sum_ij dots
__global__ __launch_bounds__(256) void reduce_k(
    const float* __restrict__ dots, float* __restrict__ s_j, float* __restrict__ s_all) {
  const int b = blockIdx.x;
  const int t = threadIdx.x;
  const float* dp = dots + (long)b * Ss * Nn;
  const int i = t >> 2, qq = t & 3;
  float s = 0.f;
  const float* rp = dp + i * Nn + qq * 256;
  for (int j = 0; j < 256; j++) s += rp[j];
  __shared__ float part[256];
  __shared__ float rowsum[64];
  part[t] = s;
  __syncthreads();
  if (t < 64) {
    const float v = part[t * 4] + part[t * 4 + 1] + part[t * 4 + 2] + part[t * 4 + 3];
    rowsum[t] = v;
    s_j[b * 64 + t] = v;
  }
  __syncthreads();
  if (t == 0) {
    float tot = 0.f;
    for (int k = 0; k < 64; k++) tot += rowsum[k];
    s_all[b] = tot;
  }
}

// attn = sigmoid(dots * s_all/s_j) -> out; inv_r = 1/(rowsum(attn)+eps)
__global__ __launch_bounds__(256) void attn_k(
    const float* __restrict__ dots, const float* __restrict__ s_j,
    const float* __restrict__ s_all, float* __restrict__ attn_out,
    float* __restrict__ inv_r) {
  const int bi = blockIdx.x;
  const int b = bi >> 6;
  const int t = threadIdx.x;
  const float ratio = s_all[b] / s_j[bi];
  const float* dp = dots + (long)bi * Nn;
  float* ap = attn_out + (long)bi * Nn;
  float s = 0.f;
#pragma unroll
  for (int qq = 0; qq < 4; qq++) {
    const int j = qq * 256 + t;
    const float x = dp[j] * ratio;
    const float a = 1.f / (1.f + expf(-x));
    ap[j] = a;
    s += a;
  }
  __shared__ float red[256];
  red[t] = s;
  __syncthreads();
  for (int off = 128; off > 0; off >>= 1) {
    if (t < off) red[t] += red[t + off];
    __syncthreads();
  }
  if (t == 0) inv_r[bi] = 1.f / (red[0] + kEps);
}

// updates[b,i,d] = inv_r[b,i] * sum_j attn[b,i,j] * inputs[b,j,d]  (fp32 register tile)
__global__ __launch_bounds__(256, 1) void updates_k2(
    const float* __restrict__ attn, const float* __restrict__ inputs,
    const float* __restrict__ inv_r, float* __restrict__ out0) {
  constexpr int NT2 = 32;       // 1024 / 32
  constexpr int BUF_F = 10240;  // floats per 40KB buffer: in@0 (8192), attT@8192 (2048)
  extern __shared__ float ldsf[];
  const int t = threadIdx.x, lam = t & 63, w = t >> 6;
  const int b = blockIdx.x >> 1, dt = blockIdx.x & 1;
  const int ig = t >> 5, dg = t & 31;
  const float* inb = inputs + (size_t)b * (Nn * Dd) + dt * 256;
  const float* attsrc = attn + (size_t)b * (Ss * Nn) + (size_t)(t >> 2) * Nn + (t & 3) * 8;
  float acc[8][8] = {};
  float4 ga0, ga1, gb0, gb1;

#define UISSUE(bufi, tile, G0, G1)                                        \
  {                                                                       \
    const int j0_ = (tile)*32;                                            \
    G0 = *(const float4*)(attsrc + j0_);                                  \
    G1 = *(const float4*)(attsrc + j0_ + 4);                              \
    float* db_ = ldsf + (bufi)*BUF_F;                                     \
    _Pragma("unroll") for (int i_ = 0; i_ < 8; i_++) {                    \
      const int row_ = i_ * 4 + w;                                        \
      gl_lds16(inb + (size_t)(j0_ + row_) * Dd + lam * 4, db_ + row_ * 256); \
    }                                                                     \
  }

#define UWRITE(bufi, G0, G1)                                              \
  {                                                                       \
    float* ab_ = ldsf + (bufi)*BUF_F + 8192;                              \
    const int col_ = t >> 2;                                              \
    const int r0_ = (t & 3) * 8;                                          \
    ab_[(r0_ + 0) * 64 + col_] = G0.x;                                    \
    ab_[(r0_ + 1) * 64 + col_] = G0.y;                                    \
    ab_[(r0_ + 2) * 64 + col_] = G0.z;                                    \
    ab_[(r0_ + 3) * 64 + col_] = G0.w;                                    \
    ab_[(r0_ + 4) * 64 + col_] = G1.x;                                    \
    ab_[(r0_ + 5) * 64 + col_] = G1.y;                                    \
    ab_[(r0_ + 6) * 64 + col_] = G1.z;                                    \
    ab_[(r0_ + 7) * 64 + col_] = G1.w;                                    \
  }

#define UCOMP(bufi)                                                       \
  {                                                                       \
    const float* db_ = ldsf + (bufi)*BUF_F;                               \
    const float* ab_ = db_ + 8192;                                        \
    _Pragma("unroll 4") for (int jj = 0; jj < 32; jj++) {                 \
      float av[8], vv[8];                                                 \
      *(float4*)&av[0] = *(const float4*)(ab_ + jj * 64 + ig * 8);        \
      *(float4*)&av[4] = *(const float4*)(ab_ + jj * 64 + ig * 8 + 4);    \
      *(float4*)&vv[0] = *(const float4*)(db_ + jj * 256 + dg * 8);       \
      *(float4*)&vv[4] = *(const float4*)(db_ + jj * 256 + dg * 8 + 4);   \
      _Pragma("unroll") for (int m_ = 0; m_ < 8; m_++)                    \
          _Pragma("unroll") for (int n_ = 0; n_ < 8; n_++)                \
              acc[m_][n_] = __builtin_fmaf(av[m_], vv[n_], acc[m_][n_]);  \
    }                                                                     \
  }

  UISSUE(0, 0, ga0, ga1);
  UISSUE(1, 1, gb0, gb1);
  UWRITE(0, ga0, ga1);

  for (int tt = 0; tt < NT2; tt += 2) {
    asm volatile("s_waitcnt vmcnt(10)" ::: "memory");
    UWRITE((tt + 1) % 3, gb0, gb1);
    asm volatile("s_waitcnt lgkmcnt(0)" ::: "memory");
    __builtin_amdgcn_s_barrier();
    __builtin_amdgcn_sched_barrier(0);
    if (tt < NT2 - 2) UISSUE((tt + 2) % 3, tt + 2, ga0, ga1);
    UCOMP(tt % 3);
    if (tt + 1 < NT2 - 1) {
      asm volatile("s_waitcnt vmcnt(10)" ::: "memory");
    } else {
      asm volatile("s_waitcnt vmcnt(0)" ::: "memory");
    }
    if (tt + 1 < NT2 - 1) UWRITE((tt + 2) % 3, ga0, ga1);
    asm volatile("s_waitcnt lgkmcnt(0)" ::: "memory");
    __builtin_amdgcn_s_barrier();
    __builtin_amdgcn_sched_barrier(0);
    if (tt + 1 < NT2 - 2) UISSUE((tt + 3) % 3, tt + 3, gb0, gb1);
    UCOMP((tt + 1) % 3);
  }
#undef UISSUE
#undef UWRITE
#undef UCOMP

#pragma unroll
  for (int m = 0; m < 8; m++) {
    const int i = ig * 8 + m;
    const float ir = inv_r[b * 64 + i];
    float4 o0, o1;
    o0.x = acc[m][0] * ir; o0.y = acc[m][1] * ir; o0.z = acc[m][2] * ir; o0.w = acc[m][3] * ir;
    o1.x = acc[m][4] * ir; o1.y = acc[m][5] * ir; o1.z = acc[m][6] * ir; o1.w = acc[m][7] * ir;
    float* op = out0 + (size_t)(b * 64 + i) * Dd + dt * 256 + dg * 8;
    *(float4*)op = o0;
    *(float4*)(op + 4) = o1;
  }
}

extern "C" void kernel_launch(void* const* d_in, const int* in_sizes, int n_in,
                              void* d_out, int out_size, void* d_ws, size_t ws_size,
                              hipStream_t stream) {
  (void)in_sizes; (void)n_in; (void)out_size; (void)ws_size;
  const float* inputs_pe = (const float*)d_in[0];
  const float* inputs = (const float*)d_in[1];
  const float* slots = (const float*)d_in[2];
  const float* W1 = (const float*)d_in[3];
  const float* b1 = (const float*)d_in[4];
  const float* W2 = (const float*)d_in[5];
  const float* b2 = (const float*)d_in[6];
  const float* W3 = (const float*)d_in[7];
  const float* b3 = (const float*)d_in[8];

  char* ws = (char*)d_ws;
  size_t off = 0;
  auto alloc = [&](size_t bytes) -> void* {
    void* p = ws + off;
    off += (bytes + 255) & ~(size_t)255;
    return p;
  };
  const size_t actB = (size_t)Bb * Nn * Dd * 2;
  unsigned short* Ahi = (unsigned short*)alloc(actB);
  unsigned short* Alo = (unsigned short*)alloc(actB);
  unsigned short* Bhi = (unsigned short*)alloc(actB);
  unsigned short* Blo = (unsigned short*)alloc(actB);
  unsigned short* w1h = (unsigned short*)alloc(Dd * Dd * 2);
  unsigned short* w1l = (unsigned short*)alloc(Dd * Dd * 2);
  unsigned short* w2h = (unsigned short*)alloc(Dd * Dd * 2);
  unsigned short* w2l = (unsigned short*)alloc(Dd * Dd * 2);
  unsigned short* w3h = (unsigned short*)alloc(Dd * Dd * 2);
  unsigned short* w3l = (unsigned short*)alloc(Dd * Dd * 2);
  unsigned short* sh = (unsigned short*)alloc(Ss * Dd * 2);
  unsigned short* sl = (unsigned short*)alloc(Ss * Dd * 2);
  float* dotsb = (float*)alloc((size_t)Bb * Ss * Nn * 4);
  float* s_j = (float*)alloc(Bb * Ss * 4);
  float* s_all = (float*)alloc(Bb * 4);
  float* inv_r = (float*)alloc(Bb * Ss * 4);

  float* out_updates = (float*)d_out;
  float* out_attn = out_updates + (size_t)Bb * Ss * Dd;

  const int kLdsG = 4 * 32 * 1024;  // 128KB ring for gemm_split3
  const int kLdsU = 3 * 40 * 1024;  // 120KB for updates_k2
  hipFuncSetAttribute(reinterpret_cast<const void*>(gemm_split3<1>),
                      hipFuncAttributeMaxDynamicSharedMemorySize, kLdsG);
  hipFuncSetAttribute(reinterpret_cast<const void*>(gemm_split3<0>),
                      hipFuncAttributeMaxDynamicSharedMemorySize, kLdsG);
  hipFuncSetAttribute(reinterpret_cast<const void*>(updates_k2),
                      hipFuncAttributeMaxDynamicSharedMemorySize, kLdsU);

  cast_split<<<4096, 256, 0, stream>>>(inputs_pe, Ahi, Alo, Bb * Nn * Dd / 4);
  cast_split<<<256, 256, 0, stream>>>(W1, w1h, w1l, Dd * Dd / 4);
  cast_split<<<256, 256, 0, stream>>>(W2, w2h, w2l, Dd * Dd / 4);
  cast_split<<<256, 256, 0, stream>>>(W3, w3h, w3l, Dd * Dd / 4);
  cast_split<<<32, 256, 0, stream>>>(slots, sh, sl, Ss * Dd / 4);

  gemm_split3<1><<<1024, 512, kLdsG, stream>>>(Ahi, Alo, w1h, w1l, b1, Bhi, Blo);
  gemm_split3<1><<<1024, 512, kLdsG, stream>>>(Bhi, Blo, w2h, w2l, b2, Ahi, Alo);
  gemm_split3<0><<<1024, 512, kLdsG, stream>>>(Ahi, Alo, w3h, w3l, b3, Bhi, Blo);

  gemm_dots_split<<<Bb * 8, 256, 0, stream>>>(sh, sl, Bhi, Blo, dotsb);
  reduce_k<<<Bb, 256, 0, stream>>>(dotsb, s_j, s_all);
  attn_k<<<Bb * Ss, 256, 0, stream>>>(dotsb, s_j, s_all, out_attn, inv_r);
  updates_k2<<<Bb * 2, 256, kLdsU, stream>>>(out_attn, inputs, inv_r, out_updates);
}

// Round 5
// 1192.201 us; speedup vs baseline: 1.1080x; 1.1080x over previous
//
#include <hip/hip_runtime.h>
#include <stdint.h>

#define Bb 128
#define Nn 1024
#define Dd 512
#define Ss 64

constexpr float kScale = 0.044194173824159216f;  // 512^-0.5
constexpr float kEps = 1e-8f;

typedef __bf16 bf16x8 __attribute__((ext_vector_type(8)));
typedef float f32x4 __attribute__((ext_vector_type(4)));
typedef float f32x16 __attribute__((ext_vector_type(16)));

__device__ inline unsigned short f2bf_rne(float x) {
  unsigned u = __builtin_bit_cast(unsigned, x);
  u += 0x7FFFu + ((u >> 16) & 1u);
  return (unsigned short)(u >> 16);
}
__device__ inline float bf2f(unsigned short h) {
  unsigned u = ((unsigned)h) << 16;
  return __builtin_bit_cast(float, u);
}

// async global->LDS, 16B per lane; LDS dest must be wave-uniform base (HW adds lane*16)
__device__ inline void gl_lds16(const void* g, void* l) {
  typedef unsigned int u32;
  auto gp = (u32 __attribute__((address_space(1)))*)(unsigned long long)(uintptr_t)g;
  auto lp = (u32 __attribute__((address_space(3)))*)(unsigned int)(uintptr_t)l;
  __builtin_amdgcn_global_load_lds(gp, lp, 16, 0, 0);
}

// f32 -> bf16 hi/lo split (a ~= hi + lo, residual ~2^-16 rel)
__global__ void cast_split(const float* __restrict__ in,
                           unsigned short* __restrict__ hi,
                           unsigned short* __restrict__ lo,
                           int n4) {
  int i = blockIdx.x * blockDim.x + threadIdx.x;
  const int stride = gridDim.x * blockDim.x;
  for (; i < n4; i += stride) {
    const float4 v = ((const float4*)in)[i];
    ushort4 h, lw;
    h.x = f2bf_rne(v.x); lw.x = f2bf_rne(v.x - bf2f(h.x));
    h.y = f2bf_rne(v.y); lw.y = f2bf_rne(v.y - bf2f(h.y));
    h.z = f2bf_rne(v.z); lw.z = f2bf_rne(v.z - bf2f(h.z));
    h.w = f2bf_rne(v.w); lw.w = f2bf_rne(v.w - bf2f(h.w));
    ((ushort4*)hi)[i] = h;
    ((ushort4*)lo)[i] = lw;
  }
}

// C[M,512] = act(A[M,512] @ W[512,512]^T + bias), split bf16 via FUSED 3-term
// (ah*bh + al*bh + ah*bl, reusing ah/bh regs; al*bl ~2^-32 dropped).
// Block 128 rows x 512 cols (full width: A read once, W L2-resident).
// 8 waves (2M x 4N), wave-tile 64x128, BK=16, v_mfma_f32_32x32x16_bf16 (24/wave/tile).
// Ring-3 x 40KB LDS (slot: Ah@0 Al@2048 Wh@4096 Wl@12288 ushorts, [row][16] tiles).
// Schedule: frag read-ahead (B(kt)+A(kt+1) drain under MFMA(kt) via reg dbuf),
// stage(kt+2) right after barrier (2-iter HBM lead), one barrier/iter, setprio,
// 1-bit read-XOR (pos = (l>>5)^(l&1)) to de-phase frag reads from gl_lds writes.
template <int ACT>
__global__ __launch_bounds__(512, 1) void gemm_fused3(
    const unsigned short* __restrict__ Ah, const unsigned short* __restrict__ Al,
    const unsigned short* __restrict__ Wh, const unsigned short* __restrict__ Wl,
    const float* __restrict__ bias,
    unsigned short* __restrict__ Ch, unsigned short* __restrict__ Cl) {
  constexpr int NT = 32;       // K=512 / BK=16
  constexpr int BUFU = 20480;  // ushorts per 40KB ring slot
  extern __shared__ unsigned short lds[];
  const int t = threadIdx.x, l = t & 63, w = t >> 6;
  const int wr = w >> 2, wc = w & 3;
  const long rowA0 = (long)blockIdx.x * 128;

  // ---- staging setup: 40 x 1KB chunks per K-tile, 5 per wave ----
  // chunk id: 0-3 Ah, 4-7 Al, 8-23 Wh, 24-39 Wl; each = 32 rows x 16k.
  // LDS offset = id*512 (arrays contiguous). Lane l: row = base + (l>>1),
  // swizzled pos p = l&1, source granule g = p ^ (row&1).
  const unsigned short* gsrc[5];
  int gdst[5];
#pragma unroll
  for (int j = 0; j < 5; j++) {
    const int id = w * 5 + j;
    const int rloc = l >> 1;
    const unsigned short* base;
    int r;
    if (id < 4)       { base = Ah + rowA0 * 512; r = id * 32 + rloc; }
    else if (id < 8)  { base = Al + rowA0 * 512; r = (id - 4) * 32 + rloc; }
    else if (id < 24) { base = Wh;               r = (id - 8) * 32 + rloc; }
    else              { base = Wl;               r = (id - 24) * 32 + rloc; }
    const int g = (l & 1) ^ (r & 1);
    gsrc[j] = base + (long)r * 512 + g * 8;
    gdst[j] = id * 512;  // + lane*8 ushorts implicit
  }

#define FSTAGE(kt)                                                       \
  {                                                                      \
    unsigned short* sb_ = lds + ((kt) % 3) * BUFU;                       \
    _Pragma("unroll") for (int j = 0; j < 5; j++)                        \
        gl_lds16(gsrc[j] + (kt) * 16, sb_ + gdst[j]);                    \
  }

  // ---- frag read addresses (ushort units) ----
  // 32x32x16 A/B frag: lane row = R0 + (l&31), k-granule g = l>>5;
  // stored pos = g ^ (row&1) = (l>>5) ^ (l&1)  (R0 multiple of 32).
  const int lane31 = l & 31;
  const int pos8 = (((l >> 5) ^ (l & 1))) * 8;
  const int arow = (wr * 64 + lane31) * 16 + pos8;          // + m*512; Al +2048
  const int brow = 4096 + (wc * 128 + lane31) * 16 + pos8;  // + n*512; Wl +8192

#define FREADA(kt, AH, AL)                                               \
  {                                                                      \
    const unsigned short* sb_ = lds + ((kt) % 3) * BUFU;                 \
    _Pragma("unroll") for (int m = 0; m < 2; m++) {                      \
      AH[m] = *(const bf16x8*)(sb_ + arow + m * 512);                    \
      AL[m] = *(const bf16x8*)(sb_ + 2048 + arow + m * 512);             \
    }                                                                    \
  }
#define FREADB(kt)                                                       \
  {                                                                      \
    const unsigned short* sb_ = lds + ((kt) % 3) * BUFU;                 \
    _Pragma("unroll") for (int n = 0; n < 4; n++) {                      \
      bh[n] = *(const bf16x8*)(sb_ + brow + n * 512);                    \
      bl[n] = *(const bf16x8*)(sb_ + 8192 + brow + n * 512);             \
    }                                                                    \
  }

#define FBODY(kt, AC, ALC, AN, ALN)                                     \
  {                                                                     \
    asm volatile("s_waitcnt vmcnt(0)" ::: "memory");                    \
    __builtin_amdgcn_s_barrier();                                       \
    __builtin_amdgcn_sched_barrier(0);                                  \
    if ((kt) + 2 < NT) FSTAGE((kt) + 2);                                \
    FREADB(kt);                                                         \
    if ((kt) + 1 < NT) FREADA((kt) + 1, AN, ALN);                       \
    __builtin_amdgcn_s_setprio(1);                                      \
    _Pragma("unroll") for (int m = 0; m < 2; m++)                       \
        _Pragma("unroll") for (int n = 0; n < 4; n++) {                 \
      acc[m][n] = __builtin_amdgcn_mfma_f32_32x32x16_bf16(AC[m], bh[n], acc[m][n], 0, 0, 0);  \
      acc[m][n] = __builtin_amdgcn_mfma_f32_32x32x16_bf16(ALC[m], bh[n], acc[m][n], 0, 0, 0); \
      acc[m][n] = __builtin_amdgcn_mfma_f32_32x32x16_bf16(AC[m], bl[n], acc[m][n], 0, 0, 0);  \
    }                                                                   \
    __builtin_amdgcn_s_setprio(0);                                      \
    __builtin_amdgcn_sched_barrier(0);                                  \
  }

  f32x16 acc[2][4] = {};
  bf16x8 ahA[2], alA[2], ahB[2], alB[2], bh[4], bl[4];

  FSTAGE(0);
  FSTAGE(1);
  asm volatile("s_waitcnt vmcnt(5)" ::: "memory");  // tile 0 landed (own 5)
  __builtin_amdgcn_s_barrier();                     // all waves' tile 0 landed
  FREADA(0, ahA, alA);

  for (int kt = 0; kt < NT; kt += 2) {
    FBODY(kt, ahA, alA, ahB, alB);
    FBODY(kt + 1, ahB, alB, ahA, alA);
  }
#undef FSTAGE
#undef FREADA
#undef FREADB
#undef FBODY

  // epilogue: C/D 32x32 layout: col = l&31, row = (r&3) + 8*(r>>2) + 4*(l>>5)
#pragma unroll
  for (int m = 0; m < 2; m++)
#pragma unroll
    for (int n = 0; n < 4; n++) {
      const int col = wc * 128 + n * 32 + (l & 31);
      const float bv = bias[col];
#pragma unroll
      for (int r = 0; r < 16; r++) {
        const long row = rowA0 + wr * 64 + m * 32 + (r & 3) + 8 * (r >> 2) + 4 * (l >> 5);
        float xv = acc[m][n][r] + bv;
        if (ACT) xv = fmaxf(xv, 0.0f);
        const unsigned short h = f2bf_rne(xv);
        const long idx = row * 512 + col;
        Ch[idx] = h;
        Cl[idx] = f2bf_rne(xv - bf2f(h));
      }
    }
}

// dots[b,64,1024] = scale * slots[64,512] @ k[b,1024,512]^T  (split bf16 MFMA, f32 out)
__global__ __launch_bounds__(256) void gemm_dots_split(
    const unsigned short* __restrict__ Qh, const unsigned short* __restrict__ Ql,
    const unsigned short* __restrict__ Kh, const unsigned short* __restrict__ Kl,
    float* __restrict__ dots) {
  constexpr int K = 512, BM = 64, BN = 128, BK = 32;
  __shared__ __align__(16) unsigned short lah[BM * BK];
  __shared__ __align__(16) unsigned short lal[BM * BK];
  __shared__ __align__(16) unsigned short lbh[BN * BK];
  __shared__ __align__(16) unsigned short lbl[BN * BK];
  const int t = threadIdx.x, l = t & 63, w = t >> 6;
  const int b = blockIdx.x >> 3, bc = blockIdx.x & 7;
  const unsigned short* kh = Kh + (long)b * Nn * Dd;
  const unsigned short* kl = Kl + (long)b * Nn * Dd;
  f32x4 acc[4][2] = {};

  for (int k0 = 0; k0 < K; k0 += BK) {
    {
      const int c = t;
      const int ga = (c >> 2) * K + k0 + (c & 3) * 8;
      const int lo = (w * 64) * 8;
      gl_lds16(Qh + ga, lah + lo);
      gl_lds16(Ql + ga, lal + lo);
    }
#pragma unroll
    for (int qq = 0; qq < 2; qq++) {
      const int c = qq * 256 + t;
      const long gb = (long)(bc * BN + (c >> 2)) * K + k0 + (c & 3) * 8;
      const int lo = (qq * 256 + w * 64) * 8;
      gl_lds16(kh + gb, lbh + lo);
      gl_lds16(kl + gb, lbl + lo);
    }
    __syncthreads();
    bf16x8 ah[4], al[4], bh[2], bl[2];
#pragma unroll
    for (int m = 0; m < 4; m++) {
      const int off = (m * 16 + (l & 15)) * BK + (l >> 4) * 8;
      ah[m] = *(const bf16x8*)(lah + off);
      al[m] = *(const bf16x8*)(lal + off);
    }
#pragma unroll
    for (int n = 0; n < 2; n++) {
      const int off = (w * 32 + n * 16 + (l & 15)) * BK + (l >> 4) * 8;
      bh[n] = *(const bf16x8*)(lbh + off);
      bl[n] = *(const bf16x8*)(lbl + off);
    }
#pragma unroll
    for (int m = 0; m < 4; m++)
#pragma unroll
      for (int n = 0; n < 2; n++) {
        acc[m][n] = __builtin_amdgcn_mfma_f32_16x16x32_bf16(ah[m], bh[n], acc[m][n], 0, 0, 0);
        acc[m][n] = __builtin_amdgcn_mfma_f32_16x16x32_bf16(al[m], bh[n], acc[m][n], 0, 0, 0);
        acc[m][n] = __builtin_amdgcn_mfma_f32_16x16x32_bf16(ah[m], bl[n], acc[m][n], 0, 0, 0);
      }
    __syncthreads();
  }
  float* dp = dots + (long)b * Ss * Nn;
#pragma unroll
  for (int m = 0; m < 4; m++) {
    const int row = m * 16 + (l >> 4) * 4;
#pragma unroll
    for (int n = 0; n < 2; n++) {
      const int col = bc * BN + w * 32 + n * 16 + (l & 15);
#pragma unroll
      for (int r = 0; r < 4; r++) dp[(long)(row + r) * Nn + col] = acc[m][n][r] * kScale;
    }
  }
}

// per-batch: s_j[b,i] = sum_j dots, s_all[b] = sum_ij dots
__global__ __launch_bounds__(256) void reduce_k(
    const float* __restrict__ dots, float* __restrict__ s_j, float* __restrict__ s_all) {
  const int b = blockIdx.x;
  const int t = threadIdx.x;
  const float* dp = dots + (long)b * Ss * Nn;
  const int i = t >> 2, qq = t & 3;
  float s = 0.f;
  const float* rp = dp + i * Nn + qq * 256;
  for (int j = 0; j < 256; j++) s += rp[j];
  __shared__ float part[256];
  __shared__ float rowsum[64];
  part[t] = s;
  __syncthreads();
  if (t < 64) {
    const float v = part[t * 4] + part[t * 4 + 1] + part[t * 4 + 2] + part[t * 4 + 3];
    rowsum[t] = v;
    s_j[b * 64 + t] = v;
  }
  __syncthreads();
  if (t == 0) {
    float tot = 0.f;
    for (int k = 0; k < 64; k++) tot += rowsum[k];
    s_all[b] = tot;
  }
}

// attn = sigmoid(dots * s_all/s_j) -> out; inv_r = 1/(rowsum(attn)+eps)
__global__ __launch_bounds__(256) void attn_k(
    const float* __restrict__ dots, const float* __restrict__ s_j,
    const float* __restrict__ s_all, float* __restrict__ attn_out,
    float* __restrict__ inv_r) {
  const int bi = blockIdx.x;
  const int b = bi >> 6;
  const int t = threadIdx.x;
  const float ratio = s_all[b] / s_j[bi];
  const float* dp = dots + (long)bi * Nn;
  float* ap = attn_out + (long)bi * Nn;
  float s = 0.f;
#pragma unroll
  for (int qq = 0; qq < 4; qq++) {
    const int j = qq * 256 + t;
    const float x = dp[j] * ratio;
    const float a = 1.f / (1.f + expf(-x));
    ap[j] = a;
    s += a;
  }
  __shared__ float red[256];
  red[t] = s;
  __syncthreads();
  for (int off = 128; off > 0; off >>= 1) {
    if (t < off) red[t] += red[t + off];
    __syncthreads();
  }
  if (t == 0) inv_r[bi] = 1.f / (red[0] + kEps);
}

// updates[b,i,d] = inv_r[b,i] * sum_j attn[b,i,j] * inputs[b,j,d]  (fp32 register tile)
__global__ __launch_bounds__(256, 1) void updates_k2(
    const float* __restrict__ attn, const float* __restrict__ inputs,
    const float* __restrict__ inv_r, float* __restrict__ out0) {
  constexpr int NT2 = 32;       // 1024 / 32
  constexpr int BUF_F = 10240;  // floats per 40KB buffer: in@0 (8192), attT@8192 (2048)
  extern __shared__ float ldsf[];
  const int t = threadIdx.x, lam = t & 63, w = t >> 6;
  const int b = blockIdx.x >> 1, dt = blockIdx.x & 1;
  const int ig = t >> 5, dg = t & 31;
  const float* inb = inputs + (size_t)b * (Nn * Dd) + dt * 256;
  const float* attsrc = attn + (size_t)b * (Ss * Nn) + (size_t)(t >> 2) * Nn + (t & 3) * 8;
  float acc[8][8] = {};
  float4 ga0, ga1, gb0, gb1;

#define UISSUE(bufi, tile, G0, G1)                                        \
  {                                                                       \
    const int j0_ = (tile)*32;                                            \
    G0 = *(const float4*)(attsrc + j0_);                                  \
    G1 = *(const float4*)(attsrc + j0_ + 4);                              \
    float* db_ = ldsf + (bufi)*BUF_F;                                     \
    _Pragma("unroll") for (int i_ = 0; i_ < 8; i_++) {                    \
      const int row_ = i_ * 4 + w;                                        \
      gl_lds16(inb + (size_t)(j0_ + row_) * Dd + lam * 4, db_ + row_ * 256); \
    }                                                                     \
  }

#define UWRITE(bufi, G0, G1)                                              \
  {                                                                       \
    float* ab_ = ldsf + (bufi)*BUF_F + 8192;                              \
    const int col_ = t >> 2;                                              \
    const int r0_ = (t & 3) * 8;                                          \
    ab_[(r0_ + 0) * 64 + col_] = G0.x;                                    \
    ab_[(r0_ + 1) * 64 + col_] = G0.y;                                    \
    ab_[(r0_ + 2) * 64 + col_] = G0.z;                                    \
    ab_[(r0_ + 3) * 64 + col_] = G0.w;                                    \
    ab_[(r0_ + 4) * 64 + col_] = G1.x;                                    \
    ab_[(r0_ + 5) * 64 + col_] = G1.y;                                    \
    ab_[(r0_ + 6) * 64 + col_] = G1.z;                                    \
    ab_[(r0_ + 7) * 64 + col_] = G1.w;                                    \
  }

#define UCOMP(bufi)                                                       \
  {                                                                       \
    const float* db_ = ldsf + (bufi)*BUF_F;                               \
    const float* ab_ = db_ + 8192;                                        \
    _Pragma("unroll 4") for (int jj = 0; jj < 32; jj++) {                 \
      float av[8], vv[8];                                                 \
      *(float4*)&av[0] = *(const float4*)(ab_ + jj * 64 + ig * 8);        \
      *(float4*)&av[4] = *(const float4*)(ab_ + jj * 64 + ig * 8 + 4);    \
      *(float4*)&vv[0] = *(const float4*)(db_ + jj * 256 + dg * 8);       \
      *(float4*)&vv[4] = *(const float4*)(db_ + jj * 256 + dg * 8 + 4);   \
      _Pragma("unroll") for (int m_ = 0; m_ < 8; m_++)                    \
          _Pragma("unroll") for (int n_ = 0; n_ < 8; n_++)                \
              acc[m_][n_] = __builtin_fmaf(av[m_], vv[n_], acc[m_][n_]);  \
    }                                                                     \
  }

  UISSUE(0, 0, ga0, ga1);
  UISSUE(1, 1, gb0, gb1);
  UWRITE(0, ga0, ga1);

  for (int tt = 0; tt < NT2; tt += 2) {
    asm volatile("s_waitcnt vmcnt(10)" ::: "memory");
    UWRITE((tt + 1) % 3, gb0, gb1);
    asm volatile("s_waitcnt lgkmcnt(0)" ::: "memory");
    __builtin_amdgcn_s_barrier();
    __builtin_amdgcn_sched_barrier(0);
    if (tt < NT2 - 2) UISSUE((tt + 2) % 3, tt + 2, ga0, ga1);
    UCOMP(tt % 3);
    if (tt + 1 < NT2 - 1) {
      asm volatile("s_waitcnt vmcnt(10)" ::: "memory");
    } else {
      asm volatile("s_waitcnt vmcnt(0)" ::: "memory");
    }
    if (tt + 1 < NT2 - 1) UWRITE((tt + 2) % 3, ga0, ga1);
    asm volatile("s_waitcnt lgkmcnt(0)" ::: "memory");
    __builtin_amdgcn_s_barrier();
    __builtin_amdgcn_sched_barrier(0);
    if (tt + 1 < NT2 - 2) UISSUE((tt + 3) % 3, tt + 3, gb0, gb1);
    UCOMP((tt + 1) % 3);
  }
#undef UISSUE
#undef UWRITE
#undef UCOMP

#pragma unroll
  for (int m = 0; m < 8; m++) {
    const int i = ig * 8 + m;
    const float ir = inv_r[b * 64 + i];
    float4 o0, o1;
    o0.x = acc[m][0] * ir; o0.y = acc[m][1] * ir; o0.z = acc[m][2] * ir; o0.w = acc[m][3] * ir;
    o1.x = acc[m][4] * ir; o1.y = acc[m][5] * ir; o1.z = acc[m][6] * ir; o1.w = acc[m][7] * ir;
    float* op = out0 + (size_t)(b * 64 + i) * Dd + dt * 256 + dg * 8;
    *(float4*)op = o0;
    *(float4*)(op + 4) = o1;
  }
}

extern "C" void kernel_launch(void* const* d_in, const int* in_sizes, int n_in,
                              void* d_out, int out_size, void* d_ws, size_t ws_size,
                              hipStream_t stream) {
  (void)in_sizes; (void)n_in; (void)out_size; (void)ws_size;
  const float* inputs_pe = (const float*)d_in[0];
  const float* inputs = (const float*)d_in[1];
  const float* slots = (const float*)d_in[2];
  const float* W1 = (const float*)d_in[3];
  const float* b1 = (const float*)d_in[4];
  const float* W2 = (const float*)d_in[5];
  const float* b2 = (const float*)d_in[6];
  const float* W3 = (const float*)d_in[7];
  const float* b3 = (const float*)d_in[8];

  char* ws = (char*)d_ws;
  size_t off = 0;
  auto alloc = [&](size_t bytes) -> void* {
    void* p = ws + off;
    off += (bytes + 255) & ~(size_t)255;
    return p;
  };
  const size_t actB = (size_t)Bb * Nn * Dd * 2;
  unsigned short* Ahi = (unsigned short*)alloc(actB);
  unsigned short* Alo = (unsigned short*)alloc(actB);
  unsigned short* Bhi = (unsigned short*)alloc(actB);
  unsigned short* Blo = (unsigned short*)alloc(actB);
  unsigned short* w1h = (unsigned short*)alloc(Dd * Dd * 2);
  unsigned short* w1l = (unsigned short*)alloc(Dd * Dd * 2);
  unsigned short* w2h = (unsigned short*)alloc(Dd * Dd * 2);
  unsigned short* w2l = (unsigned short*)alloc(Dd * Dd * 2);
  unsigned short* w3h = (unsigned short*)alloc(Dd * Dd * 2);
  unsigned short* w3l = (unsigned short*)alloc(Dd * Dd * 2);
  unsigned short* sh = (unsigned short*)alloc(Ss * Dd * 2);
  unsigned short* sl = (unsigned short*)alloc(Ss * Dd * 2);
  float* dotsb = (float*)alloc((size_t)Bb * Ss * Nn * 4);
  float* s_j = (float*)alloc(Bb * Ss * 4);
  float* s_all = (float*)alloc(Bb * 4);
  float* inv_r = (float*)alloc(Bb * Ss * 4);

  float* out_updates = (float*)d_out;
  float* out_attn = out_updates + (size_t)Bb * Ss * Dd;

  const int kLdsG = 3 * 40 * 1024;  // 120KB ring for gemm_fused3
  const int kLdsU = 3 * 40 * 1024;  // 120KB for updates_k2
  hipFuncSetAttribute(reinterpret_cast<const void*>(gemm_fused3<1>),
                      hipFuncAttributeMaxDynamicSharedMemorySize, kLdsG);
  hipFuncSetAttribute(reinterpret_cast<const void*>(gemm_fused3<0>),
                      hipFuncAttributeMaxDynamicSharedMemorySize, kLdsG);
  hipFuncSetAttribute(reinterpret_cast<const void*>(updates_k2),
                      hipFuncAttributeMaxDynamicSharedMemorySize, kLdsU);

  cast_split<<<4096, 256, 0, stream>>>(inputs_pe, Ahi, Alo, Bb * Nn * Dd / 4);
  cast_split<<<256, 256, 0, stream>>>(W1, w1h, w1l, Dd * Dd / 4);
  cast_split<<<256, 256, 0, stream>>>(W2, w2h, w2l, Dd * Dd / 4);
  cast_split<<<256, 256, 0, stream>>>(W3, w3h, w3l, Dd * Dd / 4);
  cast_split<<<32, 256, 0, stream>>>(slots, sh, sl, Ss * Dd / 4);

  gemm_fused3<1><<<1024, 512, kLdsG, stream>>>(Ahi, Alo, w1h, w1l, b1, Bhi, Blo);
  gemm_fused3<1><<<1024, 512, kLdsG, stream>>>(Bhi, Blo, w2h, w2l, b2, Ahi, Alo);
  gemm_fused3<0><<<1024, 512, kLdsG, stream>>>(Ahi, Alo, w3h, w3l, b3, Bhi, Blo);

  gemm_dots_split<<<Bb * 8, 256, 0, stream>>>(sh, sl, Bhi, Blo, dotsb);
  reduce_k<<<Bb, 256, 0, stream>>>(dotsb, s_j, s_all);
  attn_k<<<Bb * Ss, 256, 0, stream>>>(dotsb, s_j, s_all, out_attn, inv_r);
  updates_k2<<<Bb * 2, 256, kLdsU, stream>>>(out_attn, inputs, inv_r, out_updates);
}

// Round 6
// 1115.879 us; speedup vs baseline: 1.1837x; 1.0684x over previous
//
#include <hip/hip_runtime.h>
#include <stdint.h>

#define Bb 128
#define Nn 1024
#define Dd 512
#define Ss 64

constexpr float kScale = 0.044194173824159216f;  // 512^-0.5
constexpr float kEps = 1e-8f;

typedef __bf16 bf16x8 __attribute__((ext_vector_type(8)));
typedef float f32x4 __attribute__((ext_vector_type(4)));
typedef float f32x16 __attribute__((ext_vector_type(16)));

#define MFMA32 __builtin_amdgcn_mfma_f32_32x32x16_bf16

__device__ inline unsigned short f2bf_rne(float x) {
  unsigned u = __builtin_bit_cast(unsigned, x);
  u += 0x7FFFu + ((u >> 16) & 1u);
  return (unsigned short)(u >> 16);
}
__device__ inline float bf2f(unsigned short h) {
  unsigned u = ((unsigned)h) << 16;
  return __builtin_bit_cast(float, u);
}

// async global->LDS, 16B per lane; LDS dest must be wave-uniform base (HW adds lane*16)
__device__ inline void gl_lds16(const void* g, void* l) {
  typedef unsigned int u32;
  auto gp = (u32 __attribute__((address_space(1)))*)(unsigned long long)(uintptr_t)g;
  auto lp = (u32 __attribute__((address_space(3)))*)(unsigned int)(uintptr_t)l;
  __builtin_amdgcn_global_load_lds(gp, lp, 16, 0, 0);
}

// f32 -> bf16 hi/lo split (a ~= hi + lo, residual ~2^-16 rel)
__global__ void cast_split(const float* __restrict__ in,
                           unsigned short* __restrict__ hi,
                           unsigned short* __restrict__ lo,
                           int n4) {
  int i = blockIdx.x * blockDim.x + threadIdx.x;
  const int stride = gridDim.x * blockDim.x;
  for (; i < n4; i += stride) {
    const float4 v = ((const float4*)in)[i];
    ushort4 h, lw;
    h.x = f2bf_rne(v.x); lw.x = f2bf_rne(v.x - bf2f(h.x));
    h.y = f2bf_rne(v.y); lw.y = f2bf_rne(v.y - bf2f(h.y));
    h.z = f2bf_rne(v.z); lw.z = f2bf_rne(v.z - bf2f(h.z));
    h.w = f2bf_rne(v.w); lw.w = f2bf_rne(v.w - bf2f(h.w));
    ((ushort4*)hi)[i] = h;
    ((ushort4*)lo)[i] = lw;
  }
}

// C[M,512] = act(A[M,512] @ W[512,512]^T + bias), FUSED 3-term split bf16
// (ah*bh + al*bh + ah*bl; al*bl dropped). Phase-split schedule (T3+T4+T2+T5):
// BM=BN=256, BK=32, 8 waves (2Mx4N), wave-tile 128x64, 32x32x16 MFMA.
// LDS 2 x 64KB dbuf; each buffer = Ah[256][32] | Al | Wh[256][32] | Wl, 16KB each,
// [row][32] rows of 64B with granule-swizzle p = gl ^ (row&3) (2-way max on reads).
// 4 phases per K-step: (kk0,n0)(kk0,n1)(kk1,n0)(kk1,n1), each
// {ds_read -> barrier -> lgkmcnt(0) -> setprio(1) 12xMFMA setprio(0) -> barrier}.
// Stage of step kt+1 bursts in P0 (8 gl_lds/thread); step-top gate = vmcnt(0)+barrier
// (loads were issued ~3 phases earlier -> drain covered).
template <int ACT>
__global__ __launch_bounds__(512, 1) void gemm_8ph(
    const unsigned short* __restrict__ Ah, const unsigned short* __restrict__ Al,
    const unsigned short* __restrict__ Wh, const unsigned short* __restrict__ Wl,
    const float* __restrict__ bias,
    unsigned short* __restrict__ Ch, unsigned short* __restrict__ Cl) {
  constexpr int NT = 16;  // 512 / BK32
  extern __shared__ unsigned short lds[];  // 2 x 32768 ushorts
  const int t = threadIdx.x, l = t & 63, w = t >> 6;
  const int wr = w >> 2, wc = w & 3;

  // bijective XCD-chunked swizzle (1024 = 8 x 128); consecutive wg pairs share A panel
  const int wg = ((blockIdx.x & 7) << 7) + (blockIdx.x >> 3);
  const long rowA0 = (long)(wg >> 1) * 256;
  const int colB0 = (wg & 1) * 256;

  // ---- staging: 64 chunks of 1KB per K-step (16 rows x 64B); 8 per wave ----
  // chunk c: array a=c>>4 (0 Ah,1 Al,2 Wh,3 Wl), rows 16*(c&15)..+15.
  // lane l: row_rel = 16*(c&15) + (l>>2), dest granule p = l&3 (linear),
  // source granule g = p ^ (row&3) = (l&3) ^ ((l>>2)&3)  [wave-uniform].
  const unsigned short* abase[4] = {Ah + rowA0 * 512, Al + rowA0 * 512,
                                    Wh + (long)colB0 * 512, Wl + (long)colB0 * 512};
  const int gsw = (l & 3) ^ ((l >> 2) & 3);
  const unsigned short* srcp[8];
  int dstp[8];
#pragma unroll
  for (int j = 0; j < 8; j++) {
    const int c = w * 8 + j;
    srcp[j] = abase[c >> 4] + ((c & 15) * 16 + (l >> 2)) * 512 + gsw * 8;
    dstp[j] = c * 512;  // ushorts; +lane*8 implicit
  }
#define STG(kt)                                                        \
  {                                                                    \
    unsigned short* bq_ = lds + ((kt) & 1) * 32768;                    \
    _Pragma("unroll") for (int j = 0; j < 8; j++)                      \
        gl_lds16(srcp[j] + (kt) * 32, bq_ + dstp[j]);                  \
  }

  // ---- frag read offsets (ushort units) ----
  // row = R0 + (l&31) (R0 mult of 32 -> row&3 = l&3); granule gl = kk*2 + (l>>5);
  // stored pos p = gl ^ (l&3). kk=0 offset; kk=1 = offset ^ 16.
  const int p0 = ((l >> 5) ^ (l & 3)) * 8;
  int aoff[4], boff[2];
#pragma unroll
  for (int m = 0; m < 4; m++) aoff[m] = (wr * 128 + m * 32 + (l & 31)) * 32 + p0;
#pragma unroll
  for (int n = 0; n < 2; n++) boff[n] = (wc * 64 + n * 32 + (l & 31)) * 32 + p0;
  // array offsets within buffer (ushorts): Ah 0, Al 8192, Wh 16384, Wl 24576

  f32x16 acc[4][2] = {};
  bf16x8 ah[4], al[4], bh, bl;

#define PHASE_MFMA(NH)                                                 \
  {                                                                    \
    __builtin_amdgcn_s_barrier();                                      \
    asm volatile("s_waitcnt lgkmcnt(0)" ::: "memory");                 \
    __builtin_amdgcn_sched_barrier(0);                                 \
    __builtin_amdgcn_s_setprio(1);                                     \
    _Pragma("unroll") for (int m = 0; m < 4; m++) {                    \
      acc[m][NH] = MFMA32(ah[m], bh, acc[m][NH], 0, 0, 0);             \
      acc[m][NH] = MFMA32(al[m], bh, acc[m][NH], 0, 0, 0);             \
      acc[m][NH] = MFMA32(ah[m], bl, acc[m][NH], 0, 0, 0);             \
    }                                                                  \
    __builtin_amdgcn_s_setprio(0);                                     \
  }

  STG(0);

  for (int kt = 0; kt < NT; ++kt) {
    const unsigned short* bq = lds + (kt & 1) * 32768;
    // step gate: own stage(kt) landed; barrier => everyone's landed.
    asm volatile("s_waitcnt vmcnt(0)" ::: "memory");
    __builtin_amdgcn_s_barrier();
    __builtin_amdgcn_sched_barrier(0);
    // ---- P0: kk=0, n=0 (reads A(kk0) + B(kk0,n0); bursts stage kt+1) ----
#pragma unroll
    for (int m = 0; m < 4; m++) {
      ah[m] = *(const bf16x8*)(bq + aoff[m]);
      al[m] = *(const bf16x8*)(bq + 8192 + aoff[m]);
    }
    bh = *(const bf16x8*)(bq + 16384 + boff[0]);
    bl = *(const bf16x8*)(bq + 24576 + boff[0]);
    if (kt + 1 < NT) STG(kt + 1);
    PHASE_MFMA(0)
    __builtin_amdgcn_s_barrier();
    __builtin_amdgcn_sched_barrier(0);
    // ---- P1: kk=0, n=1 (A regs reused) ----
    bh = *(const bf16x8*)(bq + 16384 + boff[1]);
    bl = *(const bf16x8*)(bq + 24576 + boff[1]);
    PHASE_MFMA(1)
    __builtin_amdgcn_s_barrier();
    __builtin_amdgcn_sched_barrier(0);
    // ---- P2: kk=1, n=0 (reload A at ^16) ----
#pragma unroll
    for (int m = 0; m < 4; m++) {
      ah[m] = *(const bf16x8*)(bq + (aoff[m] ^ 16));
      al[m] = *(const bf16x8*)(bq + 8192 + (aoff[m] ^ 16));
    }
    bh = *(const bf16x8*)(bq + 16384 + (boff[0] ^ 16));
    bl = *(const bf16x8*)(bq + 24576 + (boff[0] ^ 16));
    PHASE_MFMA(0)
    __builtin_amdgcn_s_barrier();
    __builtin_amdgcn_sched_barrier(0);
    // ---- P3: kk=1, n=1 ----
    bh = *(const bf16x8*)(bq + 16384 + (boff[1] ^ 16));
    bl = *(const bf16x8*)(bq + 24576 + (boff[1] ^ 16));
    PHASE_MFMA(1)
    // no trailing barrier: next step's gate barrier covers
  }
#undef STG
#undef PHASE_MFMA

  // epilogue: C/D 32x32 layout: col = l&31, row = (r&3) + 8*(r>>2) + 4*(l>>5)
#pragma unroll
  for (int m = 0; m < 4; m++)
#pragma unroll
    for (int n = 0; n < 2; n++) {
      const int col = colB0 + wc * 64 + n * 32 + (l & 31);
      const float bv = bias[col];
#pragma unroll
      for (int r = 0; r < 16; r++) {
        const long row = rowA0 + wr * 128 + m * 32 + (r & 3) + 8 * (r >> 2) + 4 * (l >> 5);
        float xv = acc[m][n][r] + bv;
        if (ACT) xv = fmaxf(xv, 0.0f);
        const unsigned short h = f2bf_rne(xv);
        const long idx = row * 512 + col;
        Ch[idx] = h;
        Cl[idx] = f2bf_rne(xv - bf2f(h));
      }
    }
}

// dots[b,64,1024] = scale * slots[64,512] @ k[b,1024,512]^T  (split bf16 MFMA, f32 out)
__global__ __launch_bounds__(256) void gemm_dots_split(
    const unsigned short* __restrict__ Qh, const unsigned short* __restrict__ Ql,
    const unsigned short* __restrict__ Kh, const unsigned short* __restrict__ Kl,
    float* __restrict__ dots) {
  constexpr int K = 512, BM = 64, BN = 128, BK = 32;
  __shared__ __align__(16) unsigned short lah[BM * BK];
  __shared__ __align__(16) unsigned short lal[BM * BK];
  __shared__ __align__(16) unsigned short lbh[BN * BK];
  __shared__ __align__(16) unsigned short lbl[BN * BK];
  const int t = threadIdx.x, l = t & 63, w = t >> 6;
  const int b = blockIdx.x >> 3, bc = blockIdx.x & 7;
  const unsigned short* kh = Kh + (long)b * Nn * Dd;
  const unsigned short* kl = Kl + (long)b * Nn * Dd;
  f32x4 acc[4][2] = {};

  for (int k0 = 0; k0 < K; k0 += BK) {
    {
      const int c = t;
      const int ga = (c >> 2) * K + k0 + (c & 3) * 8;
      const int lo = (w * 64) * 8;
      gl_lds16(Qh + ga, lah + lo);
      gl_lds16(Ql + ga, lal + lo);
    }
#pragma unroll
    for (int qq = 0; qq < 2; qq++) {
      const int c = qq * 256 + t;
      const long gb = (long)(bc * BN + (c >> 2)) * K + k0 + (c & 3) * 8;
      const int lo = (qq * 256 + w * 64) * 8;
      gl_lds16(kh + gb, lbh + lo);
      gl_lds16(kl + gb, lbl + lo);
    }
    __syncthreads();
    bf16x8 ah[4], al[4], bh[2], bl[2];
#pragma unroll
    for (int m = 0; m < 4; m++) {
      const int off = (m * 16 + (l & 15)) * BK + (l >> 4) * 8;
      ah[m] = *(const bf16x8*)(lah + off);
      al[m] = *(const bf16x8*)(lal + off);
    }
#pragma unroll
    for (int n = 0; n < 2; n++) {
      const int off = (w * 32 + n * 16 + (l & 15)) * BK + (l >> 4) * 8;
      bh[n] = *(const bf16x8*)(lbh + off);
      bl[n] = *(const bf16x8*)(lbl + off);
    }
#pragma unroll
    for (int m = 0; m < 4; m++)
#pragma unroll
      for (int n = 0; n < 2; n++) {
        acc[m][n] = __builtin_amdgcn_mfma_f32_16x16x32_bf16(ah[m], bh[n], acc[m][n], 0, 0, 0);
        acc[m][n] = __builtin_amdgcn_mfma_f32_16x16x32_bf16(al[m], bh[n], acc[m][n], 0, 0, 0);
        acc[m][n] = __builtin_amdgcn_mfma_f32_16x16x32_bf16(ah[m], bl[n], acc[m][n], 0, 0, 0);
      }
    __syncthreads();
  }
  float* dp = dots + (long)b * Ss * Nn;
#pragma unroll
  for (int m = 0; m < 4; m++) {
    const int row = m * 16 + (l >> 4) * 4;
#pragma unroll
    for (int n = 0; n < 2; n++) {
      const int col = bc * BN + w * 32 + n * 16 + (l & 15);
#pragma unroll
      for (int r = 0; r < 4; r++) dp[(long)(row + r) * Nn + col] = acc[m][n][r] * kScale;
    }
  }
}

// per-batch: s_j[b,i] = sum_j dots, s_all[b] = sum_ij dots
__global__ __launch_bounds__(256) void reduce_k(
    const float* __restrict__ dots, float* __restrict__ s_j, float* __restrict__ s_all) {
  const int b = blockIdx.x;
  const int t = threadIdx.x;
  const float* dp = dots + (long)b * Ss * Nn;
  const int i = t >> 2, qq = t & 3;
  float s = 0.f;
  const float* rp = dp + i * Nn + qq * 256;
  for (int j = 0; j < 256; j++) s += rp[j];
  __shared__ float part[256];
  __shared__ float rowsum[64];
  part[t] = s;
  __syncthreads();
  if (t < 64) {
    const float v = part[t * 4] + part[t * 4 + 1] + part[t * 4 + 2] + part[t * 4 + 3];
    rowsum[t] = v;
    s_j[b * 64 + t] = v;
  }
  __syncthreads();
  if (t == 0) {
    float tot = 0.f;
    for (int k = 0; k < 64; k++) tot += rowsum[k];
    s_all[b] = tot;
  }
}

// attn = sigmoid(dots * s_all/s_j) -> out; inv_r = 1/(rowsum(attn)+eps)
__global__ __launch_bounds__(256) void attn_k(
    const float* __restrict__ dots, const float* __restrict__ s_j,
    const float* __restrict__ s_all, float* __restrict__ attn_out,
    float* __restrict__ inv_r) {
  const int bi = blockIdx.x;
  const int b = bi >> 6;
  const int t = threadIdx.x;
  const float ratio = s_all[b] / s_j[bi];
  const float* dp = dots + (long)bi * Nn;
  float* ap = attn_out + (long)bi * Nn;
  float s = 0.f;
#pragma unroll
  for (int qq = 0; qq < 4; qq++) {
    const int j = qq * 256 + t;
    const float x = dp[j] * ratio;
    const float a = 1.f / (1.f + expf(-x));
    ap[j] = a;
    s += a;
  }
  __shared__ float red[256];
  red[t] = s;
  __syncthreads();
  for (int off = 128; off > 0; off >>= 1) {
    if (t < off) red[t] += red[t + off];
    __syncthreads();
  }
  if (t == 0) inv_r[bi] = 1.f / (red[0] + kEps);
}

// updates[b,i,d] = inv_r[b,i] * sum_j attn[b,i,j] * inputs[b,j,d]  (fp32 register tile)
__global__ __launch_bounds__(256, 1) void updates_k2(
    const float* __restrict__ attn, const float* __restrict__ inputs,
    const float* __restrict__ inv_r, float* __restrict__ out0) {
  constexpr int NT2 = 32;       // 1024 / 32
  constexpr int BUF_F = 10240;  // floats per 40KB buffer: in@0 (8192), attT@8192 (2048)
  extern __shared__ float ldsf[];
  const int t = threadIdx.x, lam = t & 63, w = t >> 6;
  const int b = blockIdx.x >> 1, dt = blockIdx.x & 1;
  const int ig = t >> 5, dg = t & 31;
  const float* inb = inputs + (size_t)b * (Nn * Dd) + dt * 256;
  const float* attsrc = attn + (size_t)b * (Ss * Nn) + (size_t)(t >> 2) * Nn + (t & 3) * 8;
  float acc[8][8] = {};
  float4 ga0, ga1, gb0, gb1;

#define UISSUE(bufi, tile, G0, G1)                                        \
  {                                                                       \
    const int j0_ = (tile)*32;                                            \
    G0 = *(const float4*)(attsrc + j0_);                                  \
    G1 = *(const float4*)(attsrc + j0_ + 4);                              \
    float* db_ = ldsf + (bufi)*BUF_F;                                     \
    _Pragma("unroll") for (int i_ = 0; i_ < 8; i_++) {                    \
      const int row_ = i_ * 4 + w;                                        \
      gl_lds16(inb + (size_t)(j0_ + row_) * Dd + lam * 4, db_ + row_ * 256); \
    }                                                                     \
  }

#define UWRITE(bufi, G0, G1)                                              \
  {                                                                       \
    float* ab_ = ldsf + (bufi)*BUF_F + 8192;                              \
    const int col_ = t >> 2;                                              \
    const int r0_ = (t & 3) * 8;                                          \
    ab_[(r0_ + 0) * 64 + col_] = G0.x;                                    \
    ab_[(r0_ + 1) * 64 + col_] = G0.y;                                    \
    ab_[(r0_ + 2) * 64 + col_] = G0.z;                                    \
    ab_[(r0_ + 3) * 64 + col_] = G0.w;                                    \
    ab_[(r0_ + 4) * 64 + col_] = G1.x;                                    \
    ab_[(r0_ + 5) * 64 + col_] = G1.y;                                    \
    ab_[(r0_ + 6) * 64 + col_] = G1.z;                                    \
    ab_[(r0_ + 7) * 64 + col_] = G1.w;                                    \
  }

#define UCOMP(bufi)                                                       \
  {                                                                       \
    const float* db_ = ldsf + (bufi)*BUF_F;                               \
    const float* ab_ = db_ + 8192;                                        \
    _Pragma("unroll 4") for (int jj = 0; jj < 32; jj++) {                 \
      float av[8], vv[8];                                                 \
      *(float4*)&av[0] = *(const float4*)(ab_ + jj * 64 + ig * 8);        \
      *(float4*)&av[4] = *(const float4*)(ab_ + jj * 64 + ig * 8 + 4);    \
      *(float4*)&vv[0] = *(const float4*)(db_ + jj * 256 + dg * 8);       \
      *(float4*)&vv[4] = *(const float4*)(db_ + jj * 256 + dg * 8 + 4);   \
      _Pragma("unroll") for (int m_ = 0; m_ < 8; m_++)                    \
          _Pragma("unroll") for (int n_ = 0; n_ < 8; n_++)                \
              acc[m_][n_] = __builtin_fmaf(av[m_], vv[n_], acc[m_][n_]);  \
    }                                                                     \
  }

  UISSUE(0, 0, ga0, ga1);
  UISSUE(1, 1, gb0, gb1);
  UWRITE(0, ga0, ga1);

  for (int tt = 0; tt < NT2; tt += 2) {
    asm volatile("s_waitcnt vmcnt(10)" ::: "memory");
    UWRITE((tt + 1) % 3, gb0, gb1);
    asm volatile("s_waitcnt lgkmcnt(0)" ::: "memory");
    __builtin_amdgcn_s_barrier();
    __builtin_amdgcn_sched_barrier(0);
    if (tt < NT2 - 2) UISSUE((tt + 2) % 3, tt + 2, ga0, ga1);
    UCOMP(tt % 3);
    if (tt + 1 < NT2 - 1) {
      asm volatile("s_waitcnt vmcnt(10)" ::: "memory");
    } else {
      asm volatile("s_waitcnt vmcnt(0)" ::: "memory");
    }
    if (tt + 1 < NT2 - 1) UWRITE((tt + 2) % 3, ga0, ga1);
    asm volatile("s_waitcnt lgkmcnt(0)" ::: "memory");
    __builtin_amdgcn_s_barrier();
    __builtin_amdgcn_sched_barrier(0);
    if (tt + 1 < NT2 - 2) UISSUE((tt + 3) % 3, tt + 3, gb0, gb1);
    UCOMP((tt + 1) % 3);
  }
#undef UISSUE
#undef UWRITE
#undef UCOMP

#pragma unroll
  for (int m = 0; m < 8; m++) {
    const int i = ig * 8 + m;
    const float ir = inv_r[b * 64 + i];
    float4 o0, o1;
    o0.x = acc[m][0] * ir; o0.y = acc[m][1] * ir; o0.z = acc[m][2] * ir; o0.w = acc[m][3] * ir;
    o1.x = acc[m][4] * ir; o1.y = acc[m][5] * ir; o1.z = acc[m][6] * ir; o1.w = acc[m][7] * ir;
    float* op = out0 + (size_t)(b * 64 + i) * Dd + dt * 256 + dg * 8;
    *(float4*)op = o0;
    *(float4*)(op + 4) = o1;
  }
}

extern "C" void kernel_launch(void* const* d_in, const int* in_sizes, int n_in,
                              void* d_out, int out_size, void* d_ws, size_t ws_size,
                              hipStream_t stream) {
  (void)in_sizes; (void)n_in; (void)out_size; (void)ws_size;
  const float* inputs_pe = (const float*)d_in[0];
  const float* inputs = (const float*)d_in[1];
  const float* slots = (const float*)d_in[2];
  const float* W1 = (const float*)d_in[3];
  const float* b1 = (const float*)d_in[4];
  const float* W2 = (const float*)d_in[5];
  const float* b2 = (const float*)d_in[6];
  const float* W3 = (const float*)d_in[7];
  const float* b3 = (const float*)d_in[8];

  char* ws = (char*)d_ws;
  size_t off = 0;
  auto alloc = [&](size_t bytes) -> void* {
    void* p = ws + off;
    off += (bytes + 255) & ~(size_t)255;
    return p;
  };
  const size_t actB = (size_t)Bb * Nn * Dd * 2;
  unsigned short* Ahi = (unsigned short*)alloc(actB);
  unsigned short* Alo = (unsigned short*)alloc(actB);
  unsigned short* Bhi = (unsigned short*)alloc(actB);
  unsigned short* Blo = (unsigned short*)alloc(actB);
  unsigned short* w1h = (unsigned short*)alloc(Dd * Dd * 2);
  unsigned short* w1l = (unsigned short*)alloc(Dd * Dd * 2);
  unsigned short* w2h = (unsigned short*)alloc(Dd * Dd * 2);
  unsigned short* w2l = (unsigned short*)alloc(Dd * Dd * 2);
  unsigned short* w3h = (unsigned short*)alloc(Dd * Dd * 2);
  unsigned short* w3l = (unsigned short*)alloc(Dd * Dd * 2);
  unsigned short* sh = (unsigned short*)alloc(Ss * Dd * 2);
  unsigned short* sl = (unsigned short*)alloc(Ss * Dd * 2);
  float* dotsb = (float*)alloc((size_t)Bb * Ss * Nn * 4);
  float* s_j = (float*)alloc(Bb * Ss * 4);
  float* s_all = (float*)alloc(Bb * 4);
  float* inv_r = (float*)alloc(Bb * Ss * 4);

  float* out_updates = (float*)d_out;
  float* out_attn = out_updates + (size_t)Bb * Ss * Dd;

  const int kLdsG = 2 * 64 * 1024;  // 128KB dbuf for gemm_8ph
  const int kLdsU = 3 * 40 * 1024;  // 120KB for updates_k2
  hipFuncSetAttribute(reinterpret_cast<const void*>(gemm_8ph<1>),
                      hipFuncAttributeMaxDynamicSharedMemorySize, kLdsG);
  hipFuncSetAttribute(reinterpret_cast<const void*>(gemm_8ph<0>),
                      hipFuncAttributeMaxDynamicSharedMemorySize, kLdsG);
  hipFuncSetAttribute(reinterpret_cast<const void*>(updates_k2),
                      hipFuncAttributeMaxDynamicSharedMemorySize, kLdsU);

  cast_split<<<4096, 256, 0, stream>>>(inputs_pe, Ahi, Alo, Bb * Nn * Dd / 4);
  cast_split<<<256, 256, 0, stream>>>(W1, w1h, w1l, Dd * Dd / 4);
  cast_split<<<256, 256, 0, stream>>>(W2, w2h, w2l, Dd * Dd / 4);
  cast_split<<<256, 256, 0, stream>>>(W3, w3h, w3l, Dd * Dd / 4);
  cast_split<<<32, 256, 0, stream>>>(slots, sh, sl, Ss * Dd / 4);

  gemm_8ph<1><<<1024, 512, kLdsG, stream>>>(Ahi, Alo, w1h, w1l, b1, Bhi, Blo);
  gemm_8ph<1><<<1024, 512, kLdsG, stream>>>(Bhi, Blo, w2h, w2l, b2, Ahi, Alo);
  gemm_8ph<0><<<1024, 512, kLdsG, stream>>>(Ahi, Alo, w3h, w3l, b3, Bhi, Blo);

  gemm_dots_split<<<Bb * 8, 256, 0, stream>>>(sh, sl, Bhi, Blo, dotsb);
  reduce_k<<<Bb, 256, 0, stream>>>(dotsb, s_j, s_all);
  attn_k<<<Bb * Ss, 256, 0, stream>>>(dotsb, s_j, s_all, out_attn, inv_r);
  updates_k2<<<Bb * 2, 256, kLdsU, stream>>>(out_attn, inputs, inv_r, out_updates);
}

// Round 7
// 1073.561 us; speedup vs baseline: 1.2304x; 1.0394x over previous
//
#include <hip/hip_runtime.h>
#include <stdint.h>

#define Bb 128
#define Nn 1024
#define Dd 512
#define Ss 64

constexpr float kScale = 0.044194173824159216f;  // 512^-0.5
constexpr float kEps = 1e-8f;

typedef __bf16 bf16x8 __attribute__((ext_vector_type(8)));
typedef float f32x4 __attribute__((ext_vector_type(4)));
typedef float f32x16 __attribute__((ext_vector_type(16)));

#define MFMA32 __builtin_amdgcn_mfma_f32_32x32x16_bf16

__device__ inline unsigned short f2bf_rne(float x) {
  unsigned u = __builtin_bit_cast(unsigned, x);
  u += 0x7FFFu + ((u >> 16) & 1u);
  return (unsigned short)(u >> 16);
}
__device__ inline float bf2f(unsigned short h) {
  unsigned u = ((unsigned)h) << 16;
  return __builtin_bit_cast(float, u);
}

// async global->LDS, 16B per lane; LDS dest must be wave-uniform base (HW adds lane*16)
__device__ inline void gl_lds16(const void* g, void* l) {
  typedef unsigned int u32;
  auto gp = (u32 __attribute__((address_space(1)))*)(unsigned long long)(uintptr_t)g;
  auto lp = (u32 __attribute__((address_space(3)))*)(unsigned int)(uintptr_t)l;
  __builtin_amdgcn_global_load_lds(gp, lp, 16, 0, 0);
}

// f32 -> bf16 hi/lo split (a ~= hi + lo, residual ~2^-16 rel)
__global__ void cast_split(const float* __restrict__ in,
                           unsigned short* __restrict__ hi,
                           unsigned short* __restrict__ lo,
                           int n4) {
  int i = blockIdx.x * blockDim.x + threadIdx.x;
  const int stride = gridDim.x * blockDim.x;
  for (; i < n4; i += stride) {
    const float4 v = ((const float4*)in)[i];
    ushort4 h, lw;
    h.x = f2bf_rne(v.x); lw.x = f2bf_rne(v.x - bf2f(h.x));
    h.y = f2bf_rne(v.y); lw.y = f2bf_rne(v.y - bf2f(h.y));
    h.z = f2bf_rne(v.z); lw.z = f2bf_rne(v.z - bf2f(h.z));
    h.w = f2bf_rne(v.w); lw.w = f2bf_rne(v.w - bf2f(h.w));
    ((ushort4*)hi)[i] = h;
    ((ushort4*)lo)[i] = lw;
  }
}

// C[M,512] = act(A[M,512] @ W[512,512]^T + bias), FUSED 3-term split bf16
// (ah*bh + al*bh + ah*bl; al*bl dropped). Phase-split schedule (T3+T4+T2+T5):
// BM=BN=256, BK=32, 8 waves (2Mx4N), wave-tile 128x64, 32x32x16 MFMA.
// LDS 2 x 64KB dbuf; buffer = Ah[256][32] | Al | Wh[256][32] | Wl ushorts.
// Swizzle (R4-verified, 0-conflict): stored granule p = g ^ ((row>>1)&3).
// Read: 8-lane group rows r..r+7 at quad 4*(row&1) + p -> all 8 quads distinct.
// Staging: linear dest (granule l&3), inverse-swizzled source g = (l&3)^((l>>3)&3).
// 4 phases/K-step, each {ds_read -> barrier -> lgkmcnt(0) -> setprio(1) 12xMFMA
// setprio(0) -> barrier}; stage(kt+1) bursts in P0; step gate = vmcnt(0)+barrier.
template <int ACT>
__global__ __launch_bounds__(512, 1) void gemm_8ph(
    const unsigned short* __restrict__ Ah, const unsigned short* __restrict__ Al,
    const unsigned short* __restrict__ Wh, const unsigned short* __restrict__ Wl,
    const float* __restrict__ bias,
    unsigned short* __restrict__ Ch, unsigned short* __restrict__ Cl) {
  constexpr int NT = 16;  // 512 / BK32
  extern __shared__ unsigned short lds[];  // 2 x 32768 ushorts
  const int t = threadIdx.x, l = t & 63, w = t >> 6;
  const int wr = w >> 2, wc = w & 3;

  // bijective XCD-chunked swizzle (1024 = 8 x 128); consecutive wg pairs share A panel
  const int wg = ((blockIdx.x & 7) << 7) + (blockIdx.x >> 3);
  const long rowA0 = (long)(wg >> 1) * 256;
  const int colB0 = (wg & 1) * 256;

  // ---- staging: 64 chunks of 1KB per K-step (16 rows x 64B); 8 per wave ----
  // chunk c: array a=c>>4 (0 Ah,1 Al,2 Wh,3 Wl), rows 16*(c&15)..+15.
  // lane l: row_rel = 16*(c&15) + (l>>2), dest granule = l&3 (linear write),
  // source granule g = (l&3) ^ ((row>>1)&3) = (l&3) ^ ((l>>3)&3).
  const unsigned short* abase[4] = {Ah + rowA0 * 512, Al + rowA0 * 512,
                                    Wh + (long)colB0 * 512, Wl + (long)colB0 * 512};
  const int gsw = (l & 3) ^ ((l >> 3) & 3);
  const unsigned short* srcp[8];
  int dstp[8];
#pragma unroll
  for (int j = 0; j < 8; j++) {
    const int c = w * 8 + j;
    srcp[j] = abase[c >> 4] + ((c & 15) * 16 + (l >> 2)) * 512 + gsw * 8;
    dstp[j] = c * 512;  // ushorts; +lane*8 implicit
  }
#define STG(kt)                                                        \
  {                                                                    \
    unsigned short* bq_ = lds + ((kt) & 1) * 32768;                    \
    _Pragma("unroll") for (int j = 0; j < 8; j++)                      \
        gl_lds16(srcp[j] + (kt) * 32, bq_ + dstp[j]);                  \
  }

  // ---- frag read offsets (ushort units) ----
  // row = R0 + (l&31), R0 mult of 32 -> (row>>1)&3 = (l>>1)&3; granule gl = kk*2+(l>>5);
  // stored pos p = gl ^ ((l>>1)&3); kk=1 = kk=0 offset ^ 16 (granule bit1).
  const int p0 = ((l >> 5) ^ ((l >> 1) & 3)) * 8;
  int aoff[4], boff[2];
#pragma unroll
  for (int m = 0; m < 4; m++) aoff[m] = (wr * 128 + m * 32 + (l & 31)) * 32 + p0;
#pragma unroll
  for (int n = 0; n < 2; n++) boff[n] = (wc * 64 + n * 32 + (l & 31)) * 32 + p0;
  // array offsets within buffer (ushorts): Ah 0, Al 8192, Wh 16384, Wl 24576

  f32x16 acc[4][2] = {};
  bf16x8 ah[4], al[4], bh, bl;

#define PHASE_MFMA(NH)                                                 \
  {                                                                    \
    __builtin_amdgcn_s_barrier();                                      \
    asm volatile("s_waitcnt lgkmcnt(0)" ::: "memory");                 \
    __builtin_amdgcn_sched_barrier(0);                                 \
    __builtin_amdgcn_s_setprio(1);                                     \
    _Pragma("unroll") for (int m = 0; m < 4; m++) {                    \
      acc[m][NH] = MFMA32(ah[m], bh, acc[m][NH], 0, 0, 0);             \
      acc[m][NH] = MFMA32(al[m], bh, acc[m][NH], 0, 0, 0);             \
      acc[m][NH] = MFMA32(ah[m], bl, acc[m][NH], 0, 0, 0);             \
    }                                                                  \
    __builtin_amdgcn_s_setprio(0);                                     \
  }

  STG(0);

  for (int kt = 0; kt < NT; ++kt) {
    const unsigned short* bq = lds + (kt & 1) * 32768;
    // step gate: own stage(kt) landed; barrier => everyone's landed.
    asm volatile("s_waitcnt vmcnt(0)" ::: "memory");
    __builtin_amdgcn_s_barrier();
    __builtin_amdgcn_sched_barrier(0);
    // ---- P0: kk=0, n=0 (reads A(kk0) + B(kk0,n0); bursts stage kt+1) ----
#pragma unroll
    for (int m = 0; m < 4; m++) {
      ah[m] = *(const bf16x8*)(bq + aoff[m]);
      al[m] = *(const bf16x8*)(bq + 8192 + aoff[m]);
    }
    bh = *(const bf16x8*)(bq + 16384 + boff[0]);
    bl = *(const bf16x8*)(bq + 24576 + boff[0]);
    if (kt + 1 < NT) STG(kt + 1);
    PHASE_MFMA(0)
    __builtin_amdgcn_s_barrier();
    __builtin_amdgcn_sched_barrier(0);
    // ---- P1: kk=0, n=1 (A regs reused) ----
    bh = *(const bf16x8*)(bq + 16384 + boff[1]);
    bl = *(const bf16x8*)(bq + 24576 + boff[1]);
    PHASE_MFMA(1)
    __builtin_amdgcn_s_barrier();
    __builtin_amdgcn_sched_barrier(0);
    // ---- P2: kk=1, n=0 (reload A at ^16) ----
#pragma unroll
    for (int m = 0; m < 4; m++) {
      ah[m] = *(const bf16x8*)(bq + (aoff[m] ^ 16));
      al[m] = *(const bf16x8*)(bq + 8192 + (aoff[m] ^ 16));
    }
    bh = *(const bf16x8*)(bq + 16384 + (boff[0] ^ 16));
    bl = *(const bf16x8*)(bq + 24576 + (boff[0] ^ 16));
    PHASE_MFMA(0)
    __builtin_amdgcn_s_barrier();
    __builtin_amdgcn_sched_barrier(0);
    // ---- P3: kk=1, n=1 ----
    bh = *(const bf16x8*)(bq + 16384 + (boff[1] ^ 16));
    bl = *(const bf16x8*)(bq + 24576 + (boff[1] ^ 16));
    PHASE_MFMA(1)
    // no trailing barrier: next step's gate barrier covers
  }
#undef STG
#undef PHASE_MFMA

  // epilogue: C/D 32x32 layout: col = l&31, row = (r&3) + 8*(r>>2) + 4*(l>>5)
#pragma unroll
  for (int m = 0; m < 4; m++)
#pragma unroll
    for (int n = 0; n < 2; n++) {
      const int col = colB0 + wc * 64 + n * 32 + (l & 31);
      const float bv = bias[col];
#pragma unroll
      for (int r = 0; r < 16; r++) {
        const long row = rowA0 + wr * 128 + m * 32 + (r & 3) + 8 * (r >> 2) + 4 * (l >> 5);
        float xv = acc[m][n][r] + bv;
        if (ACT) xv = fmaxf(xv, 0.0f);
        const unsigned short h = f2bf_rne(xv);
        const long idx = row * 512 + col;
        Ch[idx] = h;
        Cl[idx] = f2bf_rne(xv - bf2f(h));
      }
    }
}

// dots[b,64,1024] = scale * slots[64,512] @ k[b,1024,512]^T  (split bf16 MFMA, f32 out)
__global__ __launch_bounds__(256) void gemm_dots_split(
    const unsigned short* __restrict__ Qh, const unsigned short* __restrict__ Ql,
    const unsigned short* __restrict__ Kh, const unsigned short* __restrict__ Kl,
    float* __restrict__ dots) {
  constexpr int K = 512, BM = 64, BN = 128, BK = 32;
  __shared__ __align__(16) unsigned short lah[BM * BK];
  __shared__ __align__(16) unsigned short lal[BM * BK];
  __shared__ __align__(16) unsigned short lbh[BN * BK];
  __shared__ __align__(16) unsigned short lbl[BN * BK];
  const int t = threadIdx.x, l = t & 63, w = t >> 6;
  const int b = blockIdx.x >> 3, bc = blockIdx.x & 7;
  const unsigned short* kh = Kh + (long)b * Nn * Dd;
  const unsigned short* kl = Kl + (long)b * Nn * Dd;
  f32x4 acc[4][2] = {};

  for (int k0 = 0; k0 < K; k0 += BK) {
    {
      const int c = t;
      const int ga = (c >> 2) * K + k0 + (c & 3) * 8;
      const int lo = (w * 64) * 8;
      gl_lds16(Qh + ga, lah + lo);
      gl_lds16(Ql + ga, lal + lo);
    }
#pragma unroll
    for (int qq = 0; qq < 2; qq++) {
      const int c = qq * 256 + t;
      const long gb = (long)(bc * BN + (c >> 2)) * K + k0 + (c & 3) * 8;
      const int lo = (qq * 256 + w * 64) * 8;
      gl_lds16(kh + gb, lbh + lo);
      gl_lds16(kl + gb, lbl + lo);
    }
    __syncthreads();
    bf16x8 ah[4], al[4], bh[2], bl[2];
#pragma unroll
    for (int m = 0; m < 4; m++) {
      const int off = (m * 16 + (l & 15)) * BK + (l >> 4) * 8;
      ah[m] = *(const bf16x8*)(lah + off);
      al[m] = *(const bf16x8*)(lal + off);
    }
#pragma unroll
    for (int n = 0; n < 2; n++) {
      const int off = (w * 32 + n * 16 + (l & 15)) * BK + (l >> 4) * 8;
      bh[n] = *(const bf16x8*)(lbh + off);
      bl[n] = *(const bf16x8*)(lbl + off);
    }
#pragma unroll
    for (int m = 0; m < 4; m++)
#pragma unroll
      for (int n = 0; n < 2; n++) {
        acc[m][n] = __builtin_amdgcn_mfma_f32_16x16x32_bf16(ah[m], bh[n], acc[m][n], 0, 0, 0);
        acc[m][n] = __builtin_amdgcn_mfma_f32_16x16x32_bf16(al[m], bh[n], acc[m][n], 0, 0, 0);
        acc[m][n] = __builtin_amdgcn_mfma_f32_16x16x32_bf16(ah[m], bl[n], acc[m][n], 0, 0, 0);
      }
    __syncthreads();
  }
  float* dp = dots + (long)b * Ss * Nn;
#pragma unroll
  for (int m = 0; m < 4; m++) {
    const int row = m * 16 + (l >> 4) * 4;
#pragma unroll
    for (int n = 0; n < 2; n++) {
      const int col = bc * BN + w * 32 + n * 16 + (l & 15);
#pragma unroll
      for (int r = 0; r < 4; r++) dp[(long)(row + r) * Nn + col] = acc[m][n][r] * kScale;
    }
  }
}

// per-batch: s_j[b,i] = sum_j dots, s_all[b] = sum_ij dots
__global__ __launch_bounds__(256) void reduce_k(
    const float* __restrict__ dots, float* __restrict__ s_j, float* __restrict__ s_all) {
  const int b = blockIdx.x;
  const int t = threadIdx.x;
  const float* dp = dots + (long)b * Ss * Nn;
  const int i = t >> 2, qq = t & 3;
  float s = 0.f;
  const float* rp = dp + i * Nn + qq * 256;
  for (int j = 0; j < 256; j++) s += rp[j];
  __shared__ float part[256];
  __shared__ float rowsum[64];
  part[t] = s;
  __syncthreads();
  if (t < 64) {
    const float v = part[t * 4] + part[t * 4 + 1] + part[t * 4 + 2] + part[t * 4 + 3];
    rowsum[t] = v;
    s_j[b * 64 + t] = v;
  }
  __syncthreads();
  if (t == 0) {
    float tot = 0.f;
    for (int k = 0; k < 64; k++) tot += rowsum[k];
    s_all[b] = tot;
  }
}

// attn = sigmoid(dots * s_all/s_j) -> out; inv_r = 1/(rowsum(attn)+eps)
__global__ __launch_bounds__(256) void attn_k(
    const float* __restrict__ dots, const float* __restrict__ s_j,
    const float* __restrict__ s_all, float* __restrict__ attn_out,
    float* __restrict__ inv_r) {
  const int bi = blockIdx.x;
  const int b = bi >> 6;
  const int t = threadIdx.x;
  const float ratio = s_all[b] / s_j[bi];
  const float* dp = dots + (long)bi * Nn;
  float* ap = attn_out + (long)bi * Nn;
  float s = 0.f;
#pragma unroll
  for (int qq = 0; qq < 4; qq++) {
    const int j = qq * 256 + t;
    const float x = dp[j] * ratio;
    const float a = 1.f / (1.f + expf(-x));
    ap[j] = a;
    s += a;
  }
  __shared__ float red[256];
  red[t] = s;
  __syncthreads();
  for (int off = 128; off > 0; off >>= 1) {
    if (t < off) red[t] += red[t + off];
    __syncthreads();
  }
  if (t == 0) inv_r[bi] = 1.f / (red[0] + kEps);
}

// updates[b,i,d] = inv_r[b,i] * sum_j attn[b,i,j] * inputs[b,j,d]  (fp32 register tile)
__global__ __launch_bounds__(256, 1) void updates_k2(
    const float* __restrict__ attn, const float* __restrict__ inputs,
    const float* __restrict__ inv_r, float* __restrict__ out0) {
  constexpr int NT2 = 32;       // 1024 / 32
  constexpr int BUF_F = 10240;  // floats per 40KB buffer: in@0 (8192), attT@8192 (2048)
  extern __shared__ float ldsf[];
  const int t = threadIdx.x, lam = t & 63, w = t >> 6;
  const int b = blockIdx.x >> 1, dt = blockIdx.x & 1;
  const int ig = t >> 5, dg = t & 31;
  const float* inb = inputs + (size_t)b * (Nn * Dd) + dt * 256;
  const float* attsrc = attn + (size_t)b * (Ss * Nn) + (size_t)(t >> 2) * Nn + (t & 3) * 8;
  float acc[8][8] = {};
  float4 ga0, ga1, gb0, gb1;

#define UISSUE(bufi, tile, G0, G1)                                        \
  {                                                                       \
    const int j0_ = (tile)*32;                                            \
    G0 = *(const float4*)(attsrc + j0_);                                  \
    G1 = *(const float4*)(attsrc + j0_ + 4);                              \
    float* db_ = ldsf + (bufi)*BUF_F;                                     \
    _Pragma("unroll") for (int i_ = 0; i_ < 8; i_++) {                    \
      const int row_ = i_ * 4 + w;                                        \
      gl_lds16(inb + (size_t)(j0_ + row_) * Dd + lam * 4, db_ + row_ * 256); \
    }                                                                     \
  }

#define UWRITE(bufi, G0, G1)                                              \
  {                                                                       \
    float* ab_ = ldsf + (bufi)*BUF_F + 8192;                              \
    const int col_ = t >> 2;                                              \
    const int r0_ = (t & 3) * 8;                                          \
    ab_[(r0_ + 0) * 64 + col_] = G0.x;                                    \
    ab_[(r0_ + 1) * 64 + col_] = G0.y;                                    \
    ab_[(r0_ + 2) * 64 + col_] = G0.z;                                    \
    ab_[(r0_ + 3) * 64 + col_] = G0.w;                                    \
    ab_[(r0_ + 4) * 64 + col_] = G1.x;                                    \
    ab_[(r0_ + 5) * 64 + col_] = G1.y;                                    \
    ab_[(r0_ + 6) * 64 + col_] = G1.z;                                    \
    ab_[(r0_ + 7) * 64 + col_] = G1.w;                                    \
  }

#define UCOMP(bufi)                                                       \
  {                                                                       \
    const float* db_ = ldsf + (bufi)*BUF_F;                               \
    const float* ab_ = db_ + 8192;                                        \
    _Pragma("unroll 4") for (int jj = 0; jj < 32; jj++) {                 \
      float av[8], vv[8];                                                 \
      *(float4*)&av[0] = *(const float4*)(ab_ + jj * 64 + ig * 8);        \
      *(float4*)&av[4] = *(const float4*)(ab_ + jj * 64 + ig * 8 + 4);    \
      *(float4*)&vv[0] = *(const float4*)(db_ + jj * 256 + dg * 8);       \
      *(float4*)&vv[4] = *(const float4*)(db_ + jj * 256 + dg * 8 + 4);   \
      _Pragma("unroll") for (int m_ = 0; m_ < 8; m_++)                    \
          _Pragma("unroll") for (int n_ = 0; n_ < 8; n_++)                \
              acc[m_][n_] = __builtin_fmaf(av[m_], vv[n_], acc[m_][n_]);  \
    }                                                                     \
  }

  UISSUE(0, 0, ga0, ga1);
  UISSUE(1, 1, gb0, gb1);
  UWRITE(0, ga0, ga1);

  for (int tt = 0; tt < NT2; tt += 2) {
    asm volatile("s_waitcnt vmcnt(10)" ::: "memory");
    UWRITE((tt + 1) % 3, gb0, gb1);
    asm volatile("s_waitcnt lgkmcnt(0)" ::: "memory");
    __builtin_amdgcn_s_barrier();
    __builtin_amdgcn_sched_barrier(0);
    if (tt < NT2 - 2) UISSUE((tt + 2) % 3, tt + 2, ga0, ga1);
    UCOMP(tt % 3);
    if (tt + 1 < NT2 - 1) {
      asm volatile("s_waitcnt vmcnt(10)" ::: "memory");
    } else {
      asm volatile("s_waitcnt vmcnt(0)" ::: "memory");
    }
    if (tt + 1 < NT2 - 1) UWRITE((tt + 2) % 3, ga0, ga1);
    asm volatile("s_waitcnt lgkmcnt(0)" ::: "memory");
    __builtin_amdgcn_s_barrier();
    __builtin_amdgcn_sched_barrier(0);
    if (tt + 1 < NT2 - 2) UISSUE((tt + 3) % 3, tt + 3, gb0, gb1);
    UCOMP((tt + 1) % 3);
  }
#undef UISSUE
#undef UWRITE
#undef UCOMP

#pragma unroll
  for (int m = 0; m < 8; m++) {
    const int i = ig * 8 + m;
    const float ir = inv_r[b * 64 + i];
    float4 o0, o1;
    o0.x = acc[m][0] * ir; o0.y = acc[m][1] * ir; o0.z = acc[m][2] * ir; o0.w = acc[m][3] * ir;
    o1.x = acc[m][4] * ir; o1.y = acc[m][5] * ir; o1.z = acc[m][6] * ir; o1.w = acc[m][7] * ir;
    float* op = out0 + (size_t)(b * 64 + i) * Dd + dt * 256 + dg * 8;
    *(float4*)op = o0;
    *(float4*)(op + 4) = o1;
  }
}

extern "C" void kernel_launch(void* const* d_in, const int* in_sizes, int n_in,
                              void* d_out, int out_size, void* d_ws, size_t ws_size,
                              hipStream_t stream) {
  (void)in_sizes; (void)n_in; (void)out_size; (void)ws_size;
  const float* inputs_pe = (const float*)d_in[0];
  const float* inputs = (const float*)d_in[1];
  const float* slots = (const float*)d_in[2];
  const float* W1 = (const float*)d_in[3];
  const float* b1 = (const float*)d_in[4];
  const float* W2 = (const float*)d_in[5];
  const float* b2 = (const float*)d_in[6];
  const float* W3 = (const float*)d_in[7];
  const float* b3 = (const float*)d_in[8];

  char* ws = (char*)d_ws;
  size_t off = 0;
  auto alloc = [&](size_t bytes) -> void* {
    void* p = ws + off;
    off += (bytes + 255) & ~(size_t)255;
    return p;
  };
  const size_t actB = (size_t)Bb * Nn * Dd * 2;
  unsigned short* Ahi = (unsigned short*)alloc(actB);
  unsigned short* Alo = (unsigned short*)alloc(actB);
  unsigned short* Bhi = (unsigned short*)alloc(actB);
  unsigned short* Blo = (unsigned short*)alloc(actB);
  unsigned short* w1h = (unsigned short*)alloc(Dd * Dd * 2);
  unsigned short* w1l = (unsigned short*)alloc(Dd * Dd * 2);
  unsigned short* w2h = (unsigned short*)alloc(Dd * Dd * 2);
  unsigned short* w2l = (unsigned short*)alloc(Dd * Dd * 2);
  unsigned short* w3h = (unsigned short*)alloc(Dd * Dd * 2);
  unsigned short* w3l = (unsigned short*)alloc(Dd * Dd * 2);
  unsigned short* sh = (unsigned short*)alloc(Ss * Dd * 2);
  unsigned short* sl = (unsigned short*)alloc(Ss * Dd * 2);
  float* dotsb = (float*)alloc((size_t)Bb * Ss * Nn * 4);
  float* s_j = (float*)alloc(Bb * Ss * 4);
  float* s_all = (float*)alloc(Bb * 4);
  float* inv_r = (float*)alloc(Bb * Ss * 4);

  float* out_updates = (float*)d_out;
  float* out_attn = out_updates + (size_t)Bb * Ss * Dd;

  const int kLdsG = 2 * 64 * 1024;  // 128KB dbuf for gemm_8ph
  const int kLdsU = 3 * 40 * 1024;  // 120KB for updates_k2
  hipFuncSetAttribute(reinterpret_cast<const void*>(gemm_8ph<1>),
                      hipFuncAttributeMaxDynamicSharedMemorySize, kLdsG);
  hipFuncSetAttribute(reinterpret_cast<const void*>(gemm_8ph<0>),
                      hipFuncAttributeMaxDynamicSharedMemorySize, kLdsG);
  hipFuncSetAttribute(reinterpret_cast<const void*>(updates_k2),
                      hipFuncAttributeMaxDynamicSharedMemorySize, kLdsU);

  cast_split<<<4096, 256, 0, stream>>>(inputs_pe, Ahi, Alo, Bb * Nn * Dd / 4);
  cast_split<<<256, 256, 0, stream>>>(W1, w1h, w1l, Dd * Dd / 4);
  cast_split<<<256, 256, 0, stream>>>(W2, w2h, w2l, Dd * Dd / 4);
  cast_split<<<256, 256, 0, stream>>>(W3, w3h, w3l, Dd * Dd / 4);
  cast_split<<<32, 256, 0, stream>>>(slots, sh, sl, Ss * Dd / 4);

  gemm_8ph<1><<<1024, 512, kLdsG, stream>>>(Ahi, Alo, w1h, w1l, b1, Bhi, Blo);
  gemm_8ph<1><<<1024, 512, kLdsG, stream>>>(Bhi, Blo, w2h, w2l, b2, Ahi, Alo);
  gemm_8ph<0><<<1024, 512, kLdsG, stream>>>(Ahi, Alo, w3h, w3l, b3, Bhi, Blo);

  gemm_dots_split<<<Bb * 8, 256, 0, stream>>>(sh, sl, Bhi, Blo, dotsb);
  reduce_k<<<Bb, 256, 0, stream>>>(dotsb, s_j, s_all);
  attn_k<<<Bb * Ss, 256, 0, stream>>>(dotsb, s_j, s_all, out_attn, inv_r);
  updates_k2<<<Bb * 2, 256, kLdsU, stream>>>(out_attn, inputs, inv_r, out_updates);
}